// Round 5
// baseline (870.662 us; speedup 1.0000x reference)
//
#include <hip/hip_runtime.h>
#include <hip/hip_bf16.h>

// FeaStConv x4 on MI355X.
//  (1) (xj-xi)@u = p[src]-p[dst] with p = x@u per node (p padded to [N,8]).
//  (2) out_i = sum_h (sum_j q_h x_j) @ W_h  -> gather x_j into per-head
//      aggregates Agg[N, H*Cin], then ONE dense GEMM per layer (MFMA bf16).
// Round 5:
//  - CSR build via two-level counting sort (bucket = dst>>8): kills the
//    64B-line write amplification of the old single atomic scatter
//    (101 MB -> ~14 MB of writes).
//  - agg phase B regrouped: 16 lanes/edge-row, dwordx4 gathers, 4 edges in
//    flight per wave, 48 FMA per load.
//  - fused repacks, fused scans (fewer dispatches).

#define HH 6
constexpr int NN = 50000;
constexpr int NE = 1600000;
constexpr int NBK = 196;           // buckets: dst>>8, covers 50176 nodes
constexpr int SWG = 256;           // sort workgroups
constexpr int EPW = NE / SWG;      // 6250 edges per sort wg

typedef __attribute__((ext_vector_type(8))) short bf16x8;
typedef __attribute__((ext_vector_type(4))) float f32x4;

static __device__ __forceinline__ float b2f(__hip_bfloat16 v) { return __bfloat162float(v); }
static __device__ __forceinline__ float u2f(unsigned short u) {
    return __uint_as_float(((unsigned int)u) << 16);
}
static __device__ __forceinline__ unsigned short f2bu(float v) {
    __hip_bfloat16 b = __float2bfloat16(v);
    return *reinterpret_cast<unsigned short*>(&b);
}
static __device__ __forceinline__ float lo2f(unsigned int w) {
    return __uint_as_float(w << 16);
}
static __device__ __forceinline__ float hi2f(unsigned int w) {
    return __uint_as_float(w & 0xffff0000u);
}
static __device__ __forceinline__ unsigned int pk2(float lo, float hi) {
    return ((unsigned int)f2bu(hi) << 16) | (unsigned int)f2bu(lo);
}
static __device__ __forceinline__ float ldf(const void* p, int i, int f32) {
    return f32 ? ((const float*)p)[i] : b2f(((const __hip_bfloat16*)p)[i]);
}
static __device__ __forceinline__ int ldi(const int* e32, int i, int i64) {
    return i64 ? e32[2 * i] : e32[i];
}

// ---------------- dtype detection ----------------
__global__ void k_detect(const void* pos, const void* ei, int* flags) {
    __shared__ float smax[256];
    __shared__ int anynz;
    int t = threadIdx.x;
    if (t == 0) anynz = 0;
    const __hip_bfloat16* pb = (const __hip_bfloat16*)pos;
    float m = 0.f;
    for (int i = t; i < 2048; i += 256) {
        float v = fabsf(b2f(pb[i]));
        if (v != v) v = 1e30f;
        m = fmaxf(m, v);
    }
    smax[t] = m;
    __syncthreads();
    for (int s = 128; s > 0; s >>= 1) {
        if (t < s) smax[t] = fmaxf(smax[t], smax[t + s]);
        __syncthreads();
    }
    const int* e32 = (const int*)ei;
    if (t < 128 && e32[2 * t + 1] != 0) anynz = 1;
    __syncthreads();
    if (t == 0) {
        flags[0] = (smax[0] > 1e6f) ? 1 : 0;
        flags[1] = anynz ? 0 : 1;
    }
}

// ---------------- input assembly: x0 bf16 [N,8] (pads 0) ----------------
__global__ void k_build_x0(const void* __restrict__ pos, const void* __restrict__ nrm,
                           unsigned short* __restrict__ x0b, const int* __restrict__ flags) {
    int f32 = flags[0];
    int i = blockIdx.x * blockDim.x + threadIdx.x;
    if (i >= NN) return;
#pragma unroll
    for (int j = 0; j < 3; j++) {
        x0b[i * 8 + j]     = f32 ? f2bu(((const float*)pos)[i * 3 + j])
                                 : ((const unsigned short*)pos)[i * 3 + j];
        x0b[i * 8 + 3 + j] = f32 ? f2bu(((const float*)nrm)[i * 3 + j])
                                 : ((const unsigned short*)nrm)[i * 3 + j];
    }
    x0b[i * 8 + 6] = 0;
    x0b[i * 8 + 7] = 0;
}

// ---------------- CSR build: two-level counting sort ----------------
// stage A: per-node global histogram + per-(bucket,wg) counts
__global__ void __launch_bounds__(256) k_sortA(const int* __restrict__ ei,
                                               int* __restrict__ counts,
                                               int* __restrict__ cntT,
                                               const int* __restrict__ flags) {
    __shared__ int hist[NBK];
    int i64 = flags[1];
    int t = threadIdx.x, w = blockIdx.x;
    for (int b = t; b < NBK; b += 256) hist[b] = 0;
    __syncthreads();
    int start = w * EPW, end = start + EPW;
    for (int e = start + t; e < end; e += 256) {
        int d = ldi(ei, NE + e, i64);
        atomicAdd(&counts[d], 1);
        atomicAdd(&hist[d >> 8], 1);
    }
    __syncthreads();
    for (int b = t; b < NBK; b += 256) cntT[b * SWG + w] = hist[b];
}

// two independent single-block scans (block 0: counts->offs, block 1: cntT->base2)
__global__ void __launch_bounds__(1024) k_scan2(const int* __restrict__ a0, int* __restrict__ o0,
                                                int n0, const int* __restrict__ a1,
                                                int* __restrict__ o1, int n1) {
    const int* a = (blockIdx.x == 0) ? a0 : a1;
    int* o = (blockIdx.x == 0) ? o0 : o1;
    int n = (blockIdx.x == 0) ? n0 : n1;
    __shared__ int wsum[16];
    __shared__ int s_running;
    int t = threadIdx.x;
    int lane = t & 63, wid = t >> 6;
    if (t == 0) s_running = 0;
    __syncthreads();
    for (int base = 0; base < n; base += 1024) {
        int v = (base + t < n) ? a[base + t] : 0;
        int incl = v;
#pragma unroll
        for (int off = 1; off < 64; off <<= 1) {
            int nb = __shfl_up(incl, off, 64);
            if (lane >= off) incl += nb;
        }
        if (lane == 63) wsum[wid] = incl;
        __syncthreads();
        int wprefix = 0, total = 0;
#pragma unroll
        for (int wi = 0; wi < 16; wi++) {
            int s = wsum[wi];
            if (wi < wid) wprefix += s;
            total += s;
        }
        if (base + t < n) o[base + t] = s_running + wprefix + (incl - v);
        __syncthreads();
        if (t == 0) s_running += total;
        __syncthreads();
    }
    if (t == 0) o[n] = s_running;
}

// stage B: scatter packed {dloc,src} into per-(bucket,wg) contiguous ranges
__global__ void __launch_bounds__(256) k_sortB(const int* __restrict__ ei,
                                               const int* __restrict__ base2,
                                               unsigned int* __restrict__ ebuck,
                                               const int* __restrict__ flags) {
    __shared__ int cur[NBK];
    int i64 = flags[1];
    int t = threadIdx.x, w = blockIdx.x;
    for (int b = t; b < NBK; b += 256) cur[b] = base2[b * SWG + w];
    __syncthreads();
    int start = w * EPW, end = start + EPW;
    for (int e = start + t; e < end; e += 256) {
        int s = ldi(ei, e, i64), d = ldi(ei, NE + e, i64);
        int slot = atomicAdd(&cur[d >> 8], 1);
        ebuck[slot] = (unsigned int)s | ((unsigned int)(d & 255) << 16);
    }
}

// stage C: fine scatter within one bucket (exclusive ~32KB slot region)
__global__ void __launch_bounds__(256) k_sortC(const unsigned int* __restrict__ ebuck,
                                               const int* __restrict__ base2,
                                               const int* __restrict__ offs,
                                               int* __restrict__ ssrc) {
    __shared__ int cur[256];
    int t = threadIdx.x, b = blockIdx.x;
    int gn = b * 256 + t;
    cur[t] = (gn < NN) ? offs[gn] : NE;
    __syncthreads();
    int bs = base2[b * SWG], be = base2[(b + 1) * SWG];
    for (int e = bs + t; e < be; e += 256) {
        unsigned int rec = ebuck[e];
        int slot = atomicAdd(&cur[(rec >> 16) & 255], 1);
        ssrc[slot] = (int)(rec & 0xffffu);
    }
}

// ---------------- p = x @ u  ->  p8 [N,8] fp32 (h<6 valid) ----------------
__global__ void __launch_bounds__(256) k_compute_p6(const unsigned short* __restrict__ x0b,
                                                    const void* __restrict__ u,
                                                    float* __restrict__ p8,
                                                    const int* __restrict__ flags) {
    int f32 = flags[0];
    int wave = (blockIdx.x * blockDim.x + threadIdx.x) >> 6;
    int lane = threadIdx.x & 63;
    if (wave >= NN) return;
    float acc[HH] = {0, 0, 0, 0, 0, 0};
    if (lane < 6) {
        float xv = u2f(x0b[(size_t)wave * 8 + lane]);
#pragma unroll
        for (int h = 0; h < HH; h++) acc[h] = xv * ldf(u, lane * HH + h, f32);
    }
#pragma unroll
    for (int off = 4; off > 0; off >>= 1) {
#pragma unroll
        for (int h = 0; h < HH; h++) acc[h] += __shfl_down(acc[h], off, 64);
    }
    if (lane == 0) {
#pragma unroll
        for (int h = 0; h < HH; h++) p8[(size_t)wave * 8 + h] = acc[h];
    }
}

__global__ void __launch_bounds__(256) k_compute_p128(const unsigned short* __restrict__ x,
                                                      const void* __restrict__ u,
                                                      float* __restrict__ p8,
                                                      const int* __restrict__ flags) {
    int f32 = flags[0];
    int wave = (blockIdx.x * blockDim.x + threadIdx.x) >> 6;
    int lane = threadIdx.x & 63;
    if (wave >= NN) return;
    unsigned int w = *(const unsigned int*)(x + (size_t)wave * 128 + 2 * lane);
    float x0 = lo2f(w);
    float x1 = hi2f(w);
    float acc[HH];
#pragma unroll
    for (int h = 0; h < HH; h++)
        acc[h] = x0 * ldf(u, (2 * lane) * HH + h, f32) + x1 * ldf(u, (2 * lane + 1) * HH + h, f32);
#pragma unroll
    for (int off = 32; off > 0; off >>= 1) {
#pragma unroll
        for (int h = 0; h < HH; h++) acc[h] += __shfl_down(acc[h], off, 64);
    }
    if (lane == 0) {
#pragma unroll
        for (int h = 0; h < HH; h++) p8[(size_t)wave * 8 + h] = acc[h];
    }
}

// ---------------- fused softmax + aggregation ----------------
// CIN=128: agg bf16 [N,768].  CIN=6: agg fp32 [N,36].
template <int CIN>
__global__ void __launch_bounds__(256) k_agg_fused(const unsigned short* __restrict__ xb,
                                                   const float* __restrict__ p8,
                                                   const void* __restrict__ cvec,
                                                   const int* __restrict__ ssrc,
                                                   const int* __restrict__ offs,
                                                   void* __restrict__ aggv,
                                                   const int* __restrict__ flags) {
    constexpr int ROW = (CIN == 6) ? 8 : 128;
    __shared__ uint4 qs[4][64];
    int f32 = flags[0];
    int wid = threadIdx.x >> 6, lane = threadIdx.x & 63;
    int node = (blockIdx.x * blockDim.x + threadIdx.x) >> 6;
    if (node >= NN) return;
    int s0 = offs[node], s1 = offs[node + 1];
    int deg = s1 - s0;
    float scale = 1.0f / (float)(deg > 0 ? deg : 1);
    const float* pn = p8 + (size_t)node * 8;
    float pd[HH];
#pragma unroll
    for (int h = 0; h < HH; h++) pd[h] = pn[h] - ldf(cvec, h, f32);

    int g = lane >> 4, li = lane & 15;   // CIN=128: 4 groups x 16 lanes
    float acc[8][HH] = {};               // CIN=128: 8 ch x 6 h
    float acc6 = 0.f;                    // CIN=6
    int hh6 = lane / 6, kk6 = lane - hh6 * 6;

    for (int base = s0; base < s1; base += 64) {
        // ---- phase A: lane = edge; q -> 16B LDS entry (zeroed if invalid) ----
        int e = base + lane;
        uint4 ent = {0, 0, 0, 0};
        if (e < s1) {
            int j = ssrc[e];
            const float* pj = p8 + (size_t)j * 8;
            float4 pa = *(const float4*)pj;
            float2 pb = *(const float2*)(pj + 4);
            float t0 = pa.x - pd[0], t1 = pa.y - pd[1], t2 = pa.z - pd[2];
            float t3 = pa.w - pd[3], t4 = pb.x - pd[4], t5 = pb.y - pd[5];
            float mx = fmaxf(fmaxf(fmaxf(t0, t1), fmaxf(t2, t3)), fmaxf(t4, t5));
            float q0 = __expf(t0 - mx), q1 = __expf(t1 - mx), q2 = __expf(t2 - mx);
            float q3 = __expf(t3 - mx), q4 = __expf(t4 - mx), q5 = __expf(t5 - mx);
            float inv = 1.0f / (q0 + q1 + q2 + q3 + q4 + q5);
            ent.x = pk2(q0 * inv, q1 * inv);
            ent.y = pk2(q2 * inv, q3 * inv);
            ent.z = pk2(q4 * inv, q5 * inv);
            ent.w = (unsigned int)(j * ROW);
        }
        qs[wid][lane] = ent;
        int cnt = (s1 - base < 64) ? (s1 - base) : 64;
        int cnt4 = (cnt + 3) & ~3;
        // ---- phase B ----
        if constexpr (CIN == 128) {
            for (int s = 0; s < cnt4; s += 4) {
                uint4 ee = qs[wid][s + g];
                uint4 xw = *(const uint4*)(xb + (size_t)ee.w + li * 8);
                float q[HH] = {lo2f(ee.x), hi2f(ee.x), lo2f(ee.y),
                               hi2f(ee.y), lo2f(ee.z), hi2f(ee.z)};
                float xc[8] = {lo2f(xw.x), hi2f(xw.x), lo2f(xw.y), hi2f(xw.y),
                               lo2f(xw.z), hi2f(xw.z), lo2f(xw.w), hi2f(xw.w)};
#pragma unroll
                for (int c = 0; c < 8; c++)
#pragma unroll
                    for (int h = 0; h < HH; h++) acc[c][h] += q[h] * xc[c];
            }
        } else {
            if (lane < 36) {
                for (int s = 0; s < cnt; s++) {
                    uint4 ee = qs[wid][s];
                    unsigned int qw = (hh6 < 2) ? ee.x : ((hh6 < 4) ? ee.y : ee.z);
                    float qh = (hh6 & 1) ? hi2f(qw) : lo2f(qw);
                    float xv = u2f(xb[(size_t)ee.w + kk6]);
                    acc6 += qh * xv;
                }
            }
        }
    }
    if constexpr (CIN == 128) {
        // reduce across the 4 groups -> lanes 0..15
#pragma unroll
        for (int c = 0; c < 8; c++)
#pragma unroll
            for (int h = 0; h < HH; h++) {
                float v = acc[c][h];
                v += __shfl_down(v, 32, 64);
                v += __shfl_down(v, 16, 64);
                acc[c][h] = v;
            }
        if (g == 0) {
            unsigned short* ar = (unsigned short*)aggv + (size_t)node * 768;
#pragma unroll
            for (int h = 0; h < HH; h++) {
                uint4 o;
                o.x = pk2(acc[0][h] * scale, acc[1][h] * scale);
                o.y = pk2(acc[2][h] * scale, acc[3][h] * scale);
                o.z = pk2(acc[4][h] * scale, acc[5][h] * scale);
                o.w = pk2(acc[6][h] * scale, acc[7][h] * scale);
                *(uint4*)(ar + h * 128 + li * 8) = o;
            }
        }
    } else {
        if (lane < 36) ((float*)aggv)[(size_t)node * 36 + lane] = acc6 * scale;
    }
}

// ---------------- fused weight repacks ----------------
// wstk1 fp32 [36,128]; wt2,wt3 bf16 [128,768] (B^T); wstk4 fp32 [768,3]
__global__ void k_repack_all(const void* __restrict__ W1, const void* __restrict__ W2,
                             const void* __restrict__ W3, const void* __restrict__ W4,
                             float* __restrict__ wstk1, unsigned short* __restrict__ wt2,
                             unsigned short* __restrict__ wt3, float* __restrict__ wstk4,
                             const int* __restrict__ flags) {
    int f32 = flags[0];
    int idx = blockIdx.x * blockDim.x + threadIdx.x;
    if (idx < 4608) {  // wstk1: [(h*6+k)*128 + f] = W1[k*768 + h*128 + f]
        int f = idx & 127, m = idx >> 7;
        int h = m / 6, k = m - h * 6;
        wstk1[idx] = ldf(W1, k * 768 + h * 128 + f, f32);
        return;
    }
    idx -= 4608;
    if (idx < 98304) {  // wt2[f*768 + h*128+kk] = W2[kk*768 + h*128 + f]
        int f = idx / 768, m = idx % 768;
        int h = m >> 7, kk = m & 127;
        wt2[idx] = f2bu(ldf(W2, kk * 768 + h * 128 + f, f32));
        return;
    }
    idx -= 98304;
    if (idx < 98304) {
        int f = idx / 768, m = idx % 768;
        int h = m >> 7, kk = m & 127;
        wt3[idx] = f2bu(ldf(W3, kk * 768 + h * 128 + f, f32));
        return;
    }
    idx -= 98304;
    if (idx < 2304) {  // wstk4[(h*128+k)*3 + f] = W4[k*18 + h*3 + f]
        int f = idx % 3, m = idx / 3;
        int h = m >> 7, k = m & 127;
        wstk4[idx] = ldf(W4, k * 18 + h * 3 + f, f32);
    }
}

// ---------------- layer-1 GEMM (fp32, K=36), writes bf16 x ----------------
__global__ void __launch_bounds__(256) k_gemm_f32(const float* __restrict__ A,
                                                  const float* __restrict__ B,
                                                  const void* __restrict__ bias,
                                                  unsigned short* __restrict__ C,
                                                  int M, int K, int relu,
                                                  const int* __restrict__ flags) {
    int f32 = flags[0];
    __shared__ float As[16][68];
    __shared__ float Bs[16][128];
    int tid = threadIdx.x;
    int tx = tid & 15;
    int ty = tid >> 4;
    int bm = blockIdx.x * 64;
    int arow = tid >> 2, ak = (tid & 3) * 4;
    int brow = tid >> 4, bcol = (tid & 15) * 8;
    float acc[4][8] = {};
    for (int k0 = 0; k0 < K; k0 += 16) {
        float4 av = {0, 0, 0, 0};
        int gr = bm + arow;
        if (gr < M && (k0 + ak) < K) av = *(const float4*)(A + (size_t)gr * K + k0 + ak);
        As[ak + 0][arow] = av.x;
        As[ak + 1][arow] = av.y;
        As[ak + 2][arow] = av.z;
        As[ak + 3][arow] = av.w;
        float4 bv0 = {0, 0, 0, 0}, bv1 = {0, 0, 0, 0};
        if ((k0 + brow) < K) {
            const float* bp = B + (size_t)(k0 + brow) * 128 + bcol;
            bv0 = *(const float4*)bp;
            bv1 = *(const float4*)(bp + 4);
        }
        *(float4*)&Bs[brow][bcol]     = bv0;
        *(float4*)&Bs[brow][bcol + 4] = bv1;
        __syncthreads();
#pragma unroll
        for (int kk = 0; kk < 16; kk++) {
            float a_[4], b_[8];
#pragma unroll
            for (int j = 0; j < 4; j++) a_[j] = As[kk][ty * 4 + j];
#pragma unroll
            for (int j = 0; j < 8; j++) b_[j] = Bs[kk][tx * 8 + j];
#pragma unroll
            for (int i = 0; i < 4; i++)
#pragma unroll
                for (int j = 0; j < 8; j++) acc[i][j] = fmaf(a_[i], b_[j], acc[i][j]);
        }
        __syncthreads();
    }
#pragma unroll
    for (int i = 0; i < 4; i++) {
        int row = bm + ty * 4 + i;
        if (row >= M) continue;
#pragma unroll
        for (int j = 0; j < 8; j++) {
            int col = tx * 8 + j;
            float v = acc[i][j] + ldf(bias, col, f32);
            if (relu) v = fmaxf(v, 0.f);
            C[(size_t)row * 128 + col] = f2bu(v);
        }
    }
}

// ---------------- MFMA GEMM: C[M,128] = A[M,768]bf16 @ Wt^T + bias, ReLU ----
__global__ void __launch_bounds__(256) k_gemm_mfma(const unsigned short* __restrict__ A,
                                                   const unsigned short* __restrict__ Bt,
                                                   const void* __restrict__ bias,
                                                   unsigned short* __restrict__ C,
                                                   int M, int relu,
                                                   const int* __restrict__ flags) {
    constexpr int K = 768, BK = 64;
    __shared__ unsigned short As[64][72];
    __shared__ unsigned short Bs[128][72];
    int f32 = flags[0];
    int tid = threadIdx.x;
    int lane = tid & 63, wid = tid >> 6;
    int wm = wid & 1, wn = wid >> 1;
    int bm = blockIdx.x * 64;
    int l15 = lane & 15, lq = lane >> 4;
    f32x4 acc[2][4] = {};

    for (int k0 = 0; k0 < K; k0 += BK) {
#pragma unroll
        for (int cc = 0; cc < 2; cc++) {
            int c = tid + cc * 256;
            int r = c >> 3, kc = (c & 7) * 8;
            bf16x8 av = {};
            int gr = bm + r;
            if (gr < M) av = *(const bf16x8*)(A + (size_t)gr * K + k0 + kc);
            *(bf16x8*)&As[r][kc] = av;
        }
#pragma unroll
        for (int cc = 0; cc < 4; cc++) {
            int c = tid + cc * 256;
            int n = c >> 3, kc = (c & 7) * 8;
            *(bf16x8*)&Bs[n][kc] = *(const bf16x8*)(Bt + (size_t)n * K + k0 + kc);
        }
        __syncthreads();
#pragma unroll
        for (int ks = 0; ks < BK; ks += 32) {
            int koff = ks + lq * 8;
            bf16x8 af[2], bfr[4];
#pragma unroll
            for (int tm = 0; tm < 2; tm++)
                af[tm] = *(const bf16x8*)&As[wm * 32 + tm * 16 + l15][koff];
#pragma unroll
            for (int tn = 0; tn < 4; tn++)
                bfr[tn] = *(const bf16x8*)&Bs[wn * 64 + tn * 16 + l15][koff];
#pragma unroll
            for (int tm = 0; tm < 2; tm++)
#pragma unroll
                for (int tn = 0; tn < 4; tn++)
                    acc[tm][tn] = __builtin_amdgcn_mfma_f32_16x16x32_bf16(
                        af[tm], bfr[tn], acc[tm][tn], 0, 0, 0);
        }
        __syncthreads();
    }
#pragma unroll
    for (int tm = 0; tm < 2; tm++) {
#pragma unroll
        for (int tn = 0; tn < 4; tn++) {
            int col = wn * 64 + tn * 16 + l15;
            float bv = ldf(bias, col, f32);
#pragma unroll
            for (int r = 0; r < 4; r++) {
                int row = bm + wm * 32 + tm * 16 + lq * 4 + r;
                if (row < M) {
                    float v = acc[tm][tn][r] + bv;
                    if (relu) v = fmaxf(v, 0.f);
                    C[(size_t)row * 128 + col] = f2bu(v);
                }
            }
        }
    }
}

// ---------------- final layer ----------------
__global__ void __launch_bounds__(256) k_final(const unsigned short* __restrict__ agg,
                                               const float* __restrict__ wstk,
                                               const void* __restrict__ bias,
                                               void* __restrict__ out,
                                               const int* __restrict__ flags) {
    int f32 = flags[0];
    int node = (blockIdx.x * blockDim.x + threadIdx.x) >> 6;
    int lane = threadIdx.x & 63;
    if (node >= NN) return;
    float f0 = 0, f1 = 0, f2 = 0;
    const unsigned short* ar = agg + (size_t)node * 768;
#pragma unroll
    for (int it = 0; it < 6; it++) {
        int m = it * 128 + 2 * lane;
        unsigned int w = *(const unsigned int*)(ar + m);
        float a0 = lo2f(w);
        float a1 = hi2f(w);
        f0 += a0 * wstk[m * 3 + 0] + a1 * wstk[m * 3 + 3];
        f1 += a0 * wstk[m * 3 + 1] + a1 * wstk[m * 3 + 4];
        f2 += a0 * wstk[m * 3 + 2] + a1 * wstk[m * 3 + 5];
    }
#pragma unroll
    for (int off = 32; off > 0; off >>= 1) {
        f0 += __shfl_down(f0, off, 64);
        f1 += __shfl_down(f1, off, 64);
        f2 += __shfl_down(f2, off, 64);
    }
    if (lane == 0) {
        float r0 = f0 + ldf(bias, 0, f32);
        float r1 = f1 + ldf(bias, 1, f32);
        float r2 = f2 + ldf(bias, 2, f32);
        if (f32) {
            float* o = (float*)out;
            o[(size_t)node * 3 + 0] = r0;
            o[(size_t)node * 3 + 1] = r1;
            o[(size_t)node * 3 + 2] = r2;
        } else {
            __hip_bfloat16* o = (__hip_bfloat16*)out;
            o[(size_t)node * 3 + 0] = __float2bfloat16(r0);
            o[(size_t)node * 3 + 1] = __float2bfloat16(r1);
            o[(size_t)node * 3 + 2] = __float2bfloat16(r2);
        }
    }
}

extern "C" void kernel_launch(void* const* d_in, const int* in_sizes, int n_in,
                              void* d_out, int out_size, void* d_ws, size_t ws_size,
                              hipStream_t stream) {
    (void)in_sizes; (void)n_in; (void)out_size; (void)ws_size;
    const void* pos = d_in[0];
    const void* nrm = d_in[1];
    const int* ei = (const int*)d_in[2];
    const void* W[4] = {d_in[3], d_in[7], d_in[11], d_in[15]};
    const void* U[4] = {d_in[4], d_in[8], d_in[12], d_in[16]};
    const void* Cc[4] = {d_in[5], d_in[9], d_in[13], d_in[17]};
    const void* Bb[4] = {d_in[6], d_in[10], d_in[14], d_in[18]};

    char* wp = (char*)d_ws;
    auto alloc = [&](size_t b) { void* r = (void*)wp; wp += (b + 255) & ~(size_t)255; return r; };
    unsigned short* xA  = (unsigned short*)alloc((size_t)NN * 128 * 2);
    unsigned short* xB  = (unsigned short*)alloc((size_t)NN * 128 * 2);
    unsigned short* x0b = (unsigned short*)alloc((size_t)NN * 8 * 2);
    float* p8     = (float*)alloc((size_t)NN * 8 * 4);
    int*   counts = (int*)alloc((size_t)NN * 4);
    int*   offs   = (int*)alloc((size_t)(NN + 1) * 4);
    int*   cntT   = (int*)alloc((size_t)NBK * SWG * 4);
    int*   base2  = (int*)alloc((size_t)(NBK * SWG + 1) * 4);
    int*   flags  = (int*)alloc(256);
    int*   ssrc   = (int*)alloc((size_t)NE * 4);
    unsigned int* ebuck = (unsigned int*)alloc((size_t)NE * 4);
    void*  aggv   = alloc((size_t)NN * 768 * 2);
    float* wstk1  = (float*)alloc((size_t)36 * 128 * 4);
    unsigned short* wt2 = (unsigned short*)alloc((size_t)128 * 768 * 2);
    unsigned short* wt3 = (unsigned short*)alloc((size_t)128 * 768 * 2);
    float* wstk4  = (float*)alloc((size_t)768 * 3 * 4);
    unsigned short* agg_h = (unsigned short*)aggv;
    float* agg_f = (float*)aggv;

    const int NB = (NN + 255) / 256;
    const int NWB = (NN * 64 + 255) / 256;
    const int GB = (NN + 63) / 64;

    k_detect<<<1, 256, 0, stream>>>(pos, ei, flags);
    hipMemsetAsync(counts, 0, (size_t)NN * 4, stream);
    k_sortA<<<SWG, 256, 0, stream>>>(ei, counts, cntT, flags);
    k_scan2<<<2, 1024, 0, stream>>>(counts, offs, NN, cntT, base2, NBK * SWG);
    k_sortB<<<SWG, 256, 0, stream>>>(ei, base2, ebuck, flags);
    k_sortC<<<NBK, 256, 0, stream>>>(ebuck, base2, offs, ssrc);
    k_build_x0<<<NB, 256, 0, stream>>>(pos, nrm, x0b, flags);
    k_repack_all<<<(203520 + 255) / 256, 256, 0, stream>>>(W[0], W[1], W[2], W[3],
                                                           wstk1, wt2, wt3, wstk4, flags);

    // ---- layer 1: 6 -> 128, relu ----
    k_compute_p6<<<NWB, 256, 0, stream>>>(x0b, U[0], p8, flags);
    k_agg_fused<6><<<NWB, 256, 0, stream>>>(x0b, p8, Cc[0], ssrc, offs, (void*)agg_f, flags);
    k_gemm_f32<<<GB, 256, 0, stream>>>(agg_f, wstk1, Bb[0], xA, NN, 36, 1, flags);

    // ---- layer 2: 128 -> 128, relu ----
    k_compute_p128<<<NWB, 256, 0, stream>>>(xA, U[1], p8, flags);
    k_agg_fused<128><<<NWB, 256, 0, stream>>>(xA, p8, Cc[1], ssrc, offs, (void*)agg_h, flags);
    k_gemm_mfma<<<GB, 256, 0, stream>>>(agg_h, wt2, Bb[1], xB, NN, 1, flags);

    // ---- layer 3: 128 -> 128, relu ----
    k_compute_p128<<<NWB, 256, 0, stream>>>(xB, U[2], p8, flags);
    k_agg_fused<128><<<NWB, 256, 0, stream>>>(xB, p8, Cc[2], ssrc, offs, (void*)agg_h, flags);
    k_gemm_mfma<<<GB, 256, 0, stream>>>(agg_h, wt3, Bb[2], xA, NN, 1, flags);

    // ---- layer 4: 128 -> 3 ----
    k_compute_p128<<<NWB, 256, 0, stream>>>(xA, U[3], p8, flags);
    k_agg_fused<128><<<NWB, 256, 0, stream>>>(xA, p8, Cc[3], ssrc, offs, (void*)agg_h, flags);
    k_final<<<NWB, 256, 0, stream>>>(agg_h, wstk4, Bb[3], d_out, flags);
}

// Round 6
// 845.318 us; speedup vs baseline: 1.0300x; 1.0300x over previous
//
#include <hip/hip_runtime.h>
#include <hip/hip_bf16.h>

// FeaStConv x4 on MI355X.
//  (1) (xj-xi)@u = p[src]-p[dst] with p = x@u per node (p padded to [N,8]).
//  (2) out_i = sum_h (sum_j q_h x_j) @ W_h  -> gather x_j into per-head
//      aggregates Agg[N, H*Cin], then ONE dense GEMM per layer (MFMA bf16).
// Round 6: k_agg128 rewritten around async global->LDS DMA
// (__builtin_amdgcn_global_load_lds, size=4): per 32-edge chunk, issue 32
// row-DMAs (32-deep vmcnt queue vs 4 loads in flight before), then phase B
// runs entirely from LDS (zero global latency). Round-4's low-VGPR phase-B
// shape (12 acc regs) restored — round 5's acc[8][6] regrouping halved
// occupancy and regressed 85->111 us.

#define HH 6
constexpr int NN = 50000;
constexpr int NE = 1600000;
constexpr int NBK = 196;           // buckets: dst>>8, covers 50176 nodes
constexpr int SWG = 256;           // sort workgroups
constexpr int EPW = NE / SWG;      // 6250 edges per sort wg

typedef __attribute__((ext_vector_type(8))) short bf16x8;
typedef __attribute__((ext_vector_type(4))) float f32x4;

static __device__ __forceinline__ float b2f(__hip_bfloat16 v) { return __bfloat162float(v); }
static __device__ __forceinline__ float u2f(unsigned short u) {
    return __uint_as_float(((unsigned int)u) << 16);
}
static __device__ __forceinline__ unsigned short f2bu(float v) {
    __hip_bfloat16 b = __float2bfloat16(v);
    return *reinterpret_cast<unsigned short*>(&b);
}
static __device__ __forceinline__ float lo2f(unsigned int w) {
    return __uint_as_float(w << 16);
}
static __device__ __forceinline__ float hi2f(unsigned int w) {
    return __uint_as_float(w & 0xffff0000u);
}
static __device__ __forceinline__ unsigned int pk2(float lo, float hi) {
    return ((unsigned int)f2bu(hi) << 16) | (unsigned int)f2bu(lo);
}
static __device__ __forceinline__ float ldf(const void* p, int i, int f32) {
    return f32 ? ((const float*)p)[i] : b2f(((const __hip_bfloat16*)p)[i]);
}
static __device__ __forceinline__ int ldi(const int* e32, int i, int i64) {
    return i64 ? e32[2 * i] : e32[i];
}
// async global->LDS: each lane copies 4B; lane i lands at ldst + i*4
static __device__ __forceinline__ void dma4(const unsigned short* g, unsigned short* l) {
    __builtin_amdgcn_global_load_lds(
        (const __attribute__((address_space(1))) void*)g,
        (__attribute__((address_space(3))) void*)l, 4, 0, 0);
}

// ---------------- dtype detection ----------------
__global__ void k_detect(const void* pos, const void* ei, int* flags) {
    __shared__ float smax[256];
    __shared__ int anynz;
    int t = threadIdx.x;
    if (t == 0) anynz = 0;
    const __hip_bfloat16* pb = (const __hip_bfloat16*)pos;
    float m = 0.f;
    for (int i = t; i < 2048; i += 256) {
        float v = fabsf(b2f(pb[i]));
        if (v != v) v = 1e30f;
        m = fmaxf(m, v);
    }
    smax[t] = m;
    __syncthreads();
    for (int s = 128; s > 0; s >>= 1) {
        if (t < s) smax[t] = fmaxf(smax[t], smax[t + s]);
        __syncthreads();
    }
    const int* e32 = (const int*)ei;
    if (t < 128 && e32[2 * t + 1] != 0) anynz = 1;
    __syncthreads();
    if (t == 0) {
        flags[0] = (smax[0] > 1e6f) ? 1 : 0;
        flags[1] = anynz ? 0 : 1;
    }
}

// ---------------- input assembly: x0 bf16 [N,8] (pads 0) ----------------
__global__ void k_build_x0(const void* __restrict__ pos, const void* __restrict__ nrm,
                           unsigned short* __restrict__ x0b, const int* __restrict__ flags) {
    int f32 = flags[0];
    int i = blockIdx.x * blockDim.x + threadIdx.x;
    if (i >= NN) return;
#pragma unroll
    for (int j = 0; j < 3; j++) {
        x0b[i * 8 + j]     = f32 ? f2bu(((const float*)pos)[i * 3 + j])
                                 : ((const unsigned short*)pos)[i * 3 + j];
        x0b[i * 8 + 3 + j] = f32 ? f2bu(((const float*)nrm)[i * 3 + j])
                                 : ((const unsigned short*)nrm)[i * 3 + j];
    }
    x0b[i * 8 + 6] = 0;
    x0b[i * 8 + 7] = 0;
}

// ---------------- CSR build: two-level counting sort ----------------
__global__ void __launch_bounds__(256) k_sortA(const int* __restrict__ ei,
                                               int* __restrict__ counts,
                                               int* __restrict__ cntT,
                                               const int* __restrict__ flags) {
    __shared__ int hist[NBK];
    int i64 = flags[1];
    int t = threadIdx.x, w = blockIdx.x;
    for (int b = t; b < NBK; b += 256) hist[b] = 0;
    __syncthreads();
    int start = w * EPW, end = start + EPW;
    for (int e = start + t; e < end; e += 256) {
        int d = ldi(ei, NE + e, i64);
        atomicAdd(&counts[d], 1);
        atomicAdd(&hist[d >> 8], 1);
    }
    __syncthreads();
    for (int b = t; b < NBK; b += 256) cntT[b * SWG + w] = hist[b];
}

__global__ void __launch_bounds__(1024) k_scan2(const int* __restrict__ a0, int* __restrict__ o0,
                                                int n0, const int* __restrict__ a1,
                                                int* __restrict__ o1, int n1) {
    const int* a = (blockIdx.x == 0) ? a0 : a1;
    int* o = (blockIdx.x == 0) ? o0 : o1;
    int n = (blockIdx.x == 0) ? n0 : n1;
    __shared__ int wsum[16];
    __shared__ int s_running;
    int t = threadIdx.x;
    int lane = t & 63, wid = t >> 6;
    if (t == 0) s_running = 0;
    __syncthreads();
    for (int base = 0; base < n; base += 1024) {
        int v = (base + t < n) ? a[base + t] : 0;
        int incl = v;
#pragma unroll
        for (int off = 1; off < 64; off <<= 1) {
            int nb = __shfl_up(incl, off, 64);
            if (lane >= off) incl += nb;
        }
        if (lane == 63) wsum[wid] = incl;
        __syncthreads();
        int wprefix = 0, total = 0;
#pragma unroll
        for (int wi = 0; wi < 16; wi++) {
            int s = wsum[wi];
            if (wi < wid) wprefix += s;
            total += s;
        }
        if (base + t < n) o[base + t] = s_running + wprefix + (incl - v);
        __syncthreads();
        if (t == 0) s_running += total;
        __syncthreads();
    }
    if (t == 0) o[n] = s_running;
}

__global__ void __launch_bounds__(256) k_sortB(const int* __restrict__ ei,
                                               const int* __restrict__ base2,
                                               unsigned int* __restrict__ ebuck,
                                               const int* __restrict__ flags) {
    __shared__ int cur[NBK];
    int i64 = flags[1];
    int t = threadIdx.x, w = blockIdx.x;
    for (int b = t; b < NBK; b += 256) cur[b] = base2[b * SWG + w];
    __syncthreads();
    int start = w * EPW, end = start + EPW;
    for (int e = start + t; e < end; e += 256) {
        int s = ldi(ei, e, i64), d = ldi(ei, NE + e, i64);
        int slot = atomicAdd(&cur[d >> 8], 1);
        ebuck[slot] = (unsigned int)s | ((unsigned int)(d & 255) << 16);
    }
}

__global__ void __launch_bounds__(256) k_sortC(const unsigned int* __restrict__ ebuck,
                                               const int* __restrict__ base2,
                                               const int* __restrict__ offs,
                                               int* __restrict__ ssrc) {
    __shared__ int cur[256];
    int t = threadIdx.x, b = blockIdx.x;
    int gn = b * 256 + t;
    cur[t] = (gn < NN) ? offs[gn] : NE;
    __syncthreads();
    int bs = base2[b * SWG], be = base2[(b + 1) * SWG];
    for (int e = bs + t; e < be; e += 256) {
        unsigned int rec = ebuck[e];
        int slot = atomicAdd(&cur[(rec >> 16) & 255], 1);
        ssrc[slot] = (int)(rec & 0xffffu);
    }
}

// ---------------- p = x @ u  ->  p8 [N,8] fp32 (h<6 valid) ----------------
__global__ void __launch_bounds__(256) k_compute_p6(const unsigned short* __restrict__ x0b,
                                                    const void* __restrict__ u,
                                                    float* __restrict__ p8,
                                                    const int* __restrict__ flags) {
    int f32 = flags[0];
    int wave = (blockIdx.x * blockDim.x + threadIdx.x) >> 6;
    int lane = threadIdx.x & 63;
    if (wave >= NN) return;
    float acc[HH] = {0, 0, 0, 0, 0, 0};
    if (lane < 6) {
        float xv = u2f(x0b[(size_t)wave * 8 + lane]);
#pragma unroll
        for (int h = 0; h < HH; h++) acc[h] = xv * ldf(u, lane * HH + h, f32);
    }
#pragma unroll
    for (int off = 4; off > 0; off >>= 1) {
#pragma unroll
        for (int h = 0; h < HH; h++) acc[h] += __shfl_down(acc[h], off, 64);
    }
    if (lane == 0) {
#pragma unroll
        for (int h = 0; h < HH; h++) p8[(size_t)wave * 8 + h] = acc[h];
    }
}

__global__ void __launch_bounds__(256) k_compute_p128(const unsigned short* __restrict__ x,
                                                      const void* __restrict__ u,
                                                      float* __restrict__ p8,
                                                      const int* __restrict__ flags) {
    int f32 = flags[0];
    int wave = (blockIdx.x * blockDim.x + threadIdx.x) >> 6;
    int lane = threadIdx.x & 63;
    if (wave >= NN) return;
    unsigned int w = *(const unsigned int*)(x + (size_t)wave * 128 + 2 * lane);
    float x0 = lo2f(w);
    float x1 = hi2f(w);
    float acc[HH];
#pragma unroll
    for (int h = 0; h < HH; h++)
        acc[h] = x0 * ldf(u, (2 * lane) * HH + h, f32) + x1 * ldf(u, (2 * lane + 1) * HH + h, f32);
#pragma unroll
    for (int off = 32; off > 0; off >>= 1) {
#pragma unroll
        for (int h = 0; h < HH; h++) acc[h] += __shfl_down(acc[h], off, 64);
    }
    if (lane == 0) {
#pragma unroll
        for (int h = 0; h < HH; h++) p8[(size_t)wave * 8 + h] = acc[h];
    }
}

// ---------------- fused softmax + aggregation ----------------
static __device__ __forceinline__ void edge_acc(uint4 ent, unsigned int xw,
                                                float* a0, float* a1) {
    float x0 = lo2f(xw), x1 = hi2f(xw);
    float q[6] = {lo2f(ent.x), hi2f(ent.x), lo2f(ent.y),
                  hi2f(ent.y), lo2f(ent.z), hi2f(ent.z)};
#pragma unroll
    for (int h = 0; h < HH; h++) {
        a0[h] += q[h] * x0;
        a1[h] += q[h] * x1;
    }
}

// CIN=128 with async DMA row staging. 128 threads = 2 waves, wave per node.
__global__ void __launch_bounds__(128) k_agg128(const unsigned short* __restrict__ xb,
                                                const float* __restrict__ p8,
                                                const void* __restrict__ cvec,
                                                const int* __restrict__ ssrc,
                                                const int* __restrict__ offs,
                                                unsigned short* __restrict__ agg,
                                                const int* __restrict__ flags) {
    __shared__ unsigned short stage[2][32 * 128];   // 16 KB: 32 staged rows/wave
    __shared__ uint4 qs[2][32];                     // 1 KB
    int f32 = flags[0];
    int wid = threadIdx.x >> 6, lane = threadIdx.x & 63;
    int node = (blockIdx.x * blockDim.x + threadIdx.x) >> 6;
    if (node >= NN) return;
    int s0 = offs[node], s1 = offs[node + 1];
    int deg = s1 - s0;
    float scale = 1.0f / (float)(deg > 0 ? deg : 1);
    const float* pn = p8 + (size_t)node * 8;
    float pd[HH];
#pragma unroll
    for (int h = 0; h < HH; h++) pd[h] = pn[h] - ldf(cvec, h, f32);

    float a0[HH] = {}, a1[HH] = {};
    for (int base = s0; base < s1; base += 32) {
        int cnt = (s1 - base < 32) ? (s1 - base) : 32;
        // ---- phase A: lanes 0..31 = edges; q -> 16B LDS entry ----
        int e = base + lane;
        uint4 ent = {0, 0, 0, 0};
        if (lane < 32 && e < s1) {
            int j = ssrc[e];
            const float* pj = p8 + (size_t)j * 8;
            float4 pa = *(const float4*)pj;
            float2 pb = *(const float2*)(pj + 4);
            float t0 = pa.x - pd[0], t1 = pa.y - pd[1], t2 = pa.z - pd[2];
            float t3 = pa.w - pd[3], t4 = pb.x - pd[4], t5 = pb.y - pd[5];
            float mx = fmaxf(fmaxf(fmaxf(t0, t1), fmaxf(t2, t3)), fmaxf(t4, t5));
            float q0 = __expf(t0 - mx), q1 = __expf(t1 - mx), q2 = __expf(t2 - mx);
            float q3 = __expf(t3 - mx), q4 = __expf(t4 - mx), q5 = __expf(t5 - mx);
            float inv = 1.0f / (q0 + q1 + q2 + q3 + q4 + q5);
            ent.x = pk2(q0 * inv, q1 * inv);
            ent.y = pk2(q2 * inv, q3 * inv);
            ent.z = pk2(q4 * inv, q5 * inv);
            ent.w = (unsigned int)j * 128u;          // row offset in elements
        }
        if (lane < 32) qs[wid][lane] = ent;
        // ---- issue 32 async row DMAs (vmcnt queue) ----
        const unsigned int* qraw = (const unsigned int*)&qs[wid][0];
        for (int s = 0; s < cnt; s++) {
            unsigned int rowoff = qraw[4 * s + 3];   // broadcast LDS read
            dma4(xb + (size_t)rowoff + 2 * lane, &stage[wid][s * 128]);
        }
        __builtin_amdgcn_s_waitcnt(0x0f70);          // vmcnt(0) only
        __builtin_amdgcn_sched_barrier(0);
        // ---- phase B: lane = channel pair; pure LDS ----
        int s = 0;
        for (; s + 4 <= cnt; s += 4) {
            uint4 e0 = qs[wid][s + 0];
            uint4 e1 = qs[wid][s + 1];
            uint4 e2 = qs[wid][s + 2];
            uint4 e3 = qs[wid][s + 3];
            unsigned int w0 = *(const unsigned int*)&stage[wid][(s + 0) * 128 + 2 * lane];
            unsigned int w1 = *(const unsigned int*)&stage[wid][(s + 1) * 128 + 2 * lane];
            unsigned int w2 = *(const unsigned int*)&stage[wid][(s + 2) * 128 + 2 * lane];
            unsigned int w3 = *(const unsigned int*)&stage[wid][(s + 3) * 128 + 2 * lane];
            edge_acc(e0, w0, a0, a1);
            edge_acc(e1, w1, a0, a1);
            edge_acc(e2, w2, a0, a1);
            edge_acc(e3, w3, a0, a1);
        }
        for (; s < cnt; s++) {
            uint4 ee = qs[wid][s];
            unsigned int xw = *(const unsigned int*)&stage[wid][s * 128 + 2 * lane];
            edge_acc(ee, xw, a0, a1);
        }
        __builtin_amdgcn_sched_barrier(0);           // keep next DMAs after reads
    }
    unsigned short* ar = agg + (size_t)node * 768;
#pragma unroll
    for (int h = 0; h < HH; h++) {
        *(unsigned int*)(ar + h * 128 + 2 * lane) = pk2(a0[h] * scale, a1[h] * scale);
    }
}

// CIN=6 fused softmax+agg (round-5 path): agg fp32 [N,36]
__global__ void __launch_bounds__(256) k_agg6(const unsigned short* __restrict__ xb,
                                              const float* __restrict__ p8,
                                              const void* __restrict__ cvec,
                                              const int* __restrict__ ssrc,
                                              const int* __restrict__ offs,
                                              float* __restrict__ agg,
                                              const int* __restrict__ flags) {
    __shared__ uint4 qs[4][64];
    int f32 = flags[0];
    int wid = threadIdx.x >> 6, lane = threadIdx.x & 63;
    int node = (blockIdx.x * blockDim.x + threadIdx.x) >> 6;
    if (node >= NN) return;
    int s0 = offs[node], s1 = offs[node + 1];
    int deg = s1 - s0;
    float scale = 1.0f / (float)(deg > 0 ? deg : 1);
    const float* pn = p8 + (size_t)node * 8;
    float pd[HH];
#pragma unroll
    for (int h = 0; h < HH; h++) pd[h] = pn[h] - ldf(cvec, h, f32);
    float acc6 = 0.f;
    int hh6 = lane / 6, kk6 = lane - hh6 * 6;
    for (int base = s0; base < s1; base += 64) {
        int e = base + lane;
        uint4 ent = {0, 0, 0, 0};
        if (e < s1) {
            int j = ssrc[e];
            const float* pj = p8 + (size_t)j * 8;
            float4 pa = *(const float4*)pj;
            float2 pb = *(const float2*)(pj + 4);
            float t0 = pa.x - pd[0], t1 = pa.y - pd[1], t2 = pa.z - pd[2];
            float t3 = pa.w - pd[3], t4 = pb.x - pd[4], t5 = pb.y - pd[5];
            float mx = fmaxf(fmaxf(fmaxf(t0, t1), fmaxf(t2, t3)), fmaxf(t4, t5));
            float q0 = __expf(t0 - mx), q1 = __expf(t1 - mx), q2 = __expf(t2 - mx);
            float q3 = __expf(t3 - mx), q4 = __expf(t4 - mx), q5 = __expf(t5 - mx);
            float inv = 1.0f / (q0 + q1 + q2 + q3 + q4 + q5);
            ent.x = pk2(q0 * inv, q1 * inv);
            ent.y = pk2(q2 * inv, q3 * inv);
            ent.z = pk2(q4 * inv, q5 * inv);
            ent.w = (unsigned int)j * 8u;
        }
        qs[wid][lane] = ent;
        int cnt = (s1 - base < 64) ? (s1 - base) : 64;
        if (lane < 36) {
            for (int s = 0; s < cnt; s++) {
                uint4 ee = qs[wid][s];
                unsigned int qw = (hh6 < 2) ? ee.x : ((hh6 < 4) ? ee.y : ee.z);
                float qh = (hh6 & 1) ? hi2f(qw) : lo2f(qw);
                float xv = u2f(xb[(size_t)ee.w + kk6]);
                acc6 += qh * xv;
            }
        }
    }
    if (lane < 36) agg[(size_t)node * 36 + lane] = acc6 * scale;
}

// ---------------- fused weight repacks ----------------
__global__ void k_repack_all(const void* __restrict__ W1, const void* __restrict__ W2,
                             const void* __restrict__ W3, const void* __restrict__ W4,
                             float* __restrict__ wstk1, unsigned short* __restrict__ wt2,
                             unsigned short* __restrict__ wt3, float* __restrict__ wstk4,
                             const int* __restrict__ flags) {
    int f32 = flags[0];
    int idx = blockIdx.x * blockDim.x + threadIdx.x;
    if (idx < 4608) {
        int f = idx & 127, m = idx >> 7;
        int h = m / 6, k = m - h * 6;
        wstk1[idx] = ldf(W1, k * 768 + h * 128 + f, f32);
        return;
    }
    idx -= 4608;
    if (idx < 98304) {
        int f = idx / 768, m = idx % 768;
        int h = m >> 7, kk = m & 127;
        wt2[idx] = f2bu(ldf(W2, kk * 768 + h * 128 + f, f32));
        return;
    }
    idx -= 98304;
    if (idx < 98304) {
        int f = idx / 768, m = idx % 768;
        int h = m >> 7, kk = m & 127;
        wt3[idx] = f2bu(ldf(W3, kk * 768 + h * 128 + f, f32));
        return;
    }
    idx -= 98304;
    if (idx < 2304) {
        int f = idx % 3, m = idx / 3;
        int h = m >> 7, k = m & 127;
        wstk4[idx] = ldf(W4, k * 18 + h * 3 + f, f32);
    }
}

// ---------------- layer-1 GEMM (fp32, K=36), writes bf16 x ----------------
__global__ void __launch_bounds__(256) k_gemm_f32(const float* __restrict__ A,
                                                  const float* __restrict__ B,
                                                  const void* __restrict__ bias,
                                                  unsigned short* __restrict__ C,
                                                  int M, int K, int relu,
                                                  const int* __restrict__ flags) {
    int f32 = flags[0];
    __shared__ float As[16][68];
    __shared__ float Bs[16][128];
    int tid = threadIdx.x;
    int tx = tid & 15;
    int ty = tid >> 4;
    int bm = blockIdx.x * 64;
    int arow = tid >> 2, ak = (tid & 3) * 4;
    int brow = tid >> 4, bcol = (tid & 15) * 8;
    float acc[4][8] = {};
    for (int k0 = 0; k0 < K; k0 += 16) {
        float4 av = {0, 0, 0, 0};
        int gr = bm + arow;
        if (gr < M && (k0 + ak) < K) av = *(const float4*)(A + (size_t)gr * K + k0 + ak);
        As[ak + 0][arow] = av.x;
        As[ak + 1][arow] = av.y;
        As[ak + 2][arow] = av.z;
        As[ak + 3][arow] = av.w;
        float4 bv0 = {0, 0, 0, 0}, bv1 = {0, 0, 0, 0};
        if ((k0 + brow) < K) {
            const float* bp = B + (size_t)(k0 + brow) * 128 + bcol;
            bv0 = *(const float4*)bp;
            bv1 = *(const float4*)(bp + 4);
        }
        *(float4*)&Bs[brow][bcol]     = bv0;
        *(float4*)&Bs[brow][bcol + 4] = bv1;
        __syncthreads();
#pragma unroll
        for (int kk = 0; kk < 16; kk++) {
            float a_[4], b_[8];
#pragma unroll
            for (int j = 0; j < 4; j++) a_[j] = As[kk][ty * 4 + j];
#pragma unroll
            for (int j = 0; j < 8; j++) b_[j] = Bs[kk][tx * 8 + j];
#pragma unroll
            for (int i = 0; i < 4; i++)
#pragma unroll
                for (int j = 0; j < 8; j++) acc[i][j] = fmaf(a_[i], b_[j], acc[i][j]);
        }
        __syncthreads();
    }
#pragma unroll
    for (int i = 0; i < 4; i++) {
        int row = bm + ty * 4 + i;
        if (row >= M) continue;
#pragma unroll
        for (int j = 0; j < 8; j++) {
            int col = tx * 8 + j;
            float v = acc[i][j] + ldf(bias, col, f32);
            if (relu) v = fmaxf(v, 0.f);
            C[(size_t)row * 128 + col] = f2bu(v);
        }
    }
}

// ---------------- MFMA GEMM: C[M,128] = A[M,768]bf16 @ Wt^T + bias, ReLU ----
__global__ void __launch_bounds__(256) k_gemm_mfma(const unsigned short* __restrict__ A,
                                                   const unsigned short* __restrict__ Bt,
                                                   const void* __restrict__ bias,
                                                   unsigned short* __restrict__ C,
                                                   int M, int relu,
                                                   const int* __restrict__ flags) {
    constexpr int K = 768, BK = 64;
    __shared__ unsigned short As[64][72];
    __shared__ unsigned short Bs[128][72];
    int f32 = flags[0];
    int tid = threadIdx.x;
    int lane = tid & 63, wid = tid >> 6;
    int wm = wid & 1, wn = wid >> 1;
    int bm = blockIdx.x * 64;
    int l15 = lane & 15, lq = lane >> 4;
    f32x4 acc[2][4] = {};

    for (int k0 = 0; k0 < K; k0 += BK) {
#pragma unroll
        for (int cc = 0; cc < 2; cc++) {
            int c = tid + cc * 256;
            int r = c >> 3, kc = (c & 7) * 8;
            bf16x8 av = {};
            int gr = bm + r;
            if (gr < M) av = *(const bf16x8*)(A + (size_t)gr * K + k0 + kc);
            *(bf16x8*)&As[r][kc] = av;
        }
#pragma unroll
        for (int cc = 0; cc < 4; cc++) {
            int c = tid + cc * 256;
            int n = c >> 3, kc = (c & 7) * 8;
            *(bf16x8*)&Bs[n][kc] = *(const bf16x8*)(Bt + (size_t)n * K + k0 + kc);
        }
        __syncthreads();
#pragma unroll
        for (int ks = 0; ks < BK; ks += 32) {
            int koff = ks + lq * 8;
            bf16x8 af[2], bfr[4];
#pragma unroll
            for (int tm = 0; tm < 2; tm++)
                af[tm] = *(const bf16x8*)&As[wm * 32 + tm * 16 + l15][koff];
#pragma unroll
            for (int tn = 0; tn < 4; tn++)
                bfr[tn] = *(const bf16x8*)&Bs[wn * 64 + tn * 16 + l15][koff];
#pragma unroll
            for (int tm = 0; tm < 2; tm++)
#pragma unroll
                for (int tn = 0; tn < 4; tn++)
                    acc[tm][tn] = __builtin_amdgcn_mfma_f32_16x16x32_bf16(
                        af[tm], bfr[tn], acc[tm][tn], 0, 0, 0);
        }
        __syncthreads();
    }
#pragma unroll
    for (int tm = 0; tm < 2; tm++) {
#pragma unroll
        for (int tn = 0; tn < 4; tn++) {
            int col = wn * 64 + tn * 16 + l15;
            float bv = ldf(bias, col, f32);
#pragma unroll
            for (int r = 0; r < 4; r++) {
                int row = bm + wm * 32 + tm * 16 + lq * 4 + r;
                if (row < M) {
                    float v = acc[tm][tn][r] + bv;
                    if (relu) v = fmaxf(v, 0.f);
                    C[(size_t)row * 128 + col] = f2bu(v);
                }
            }
        }
    }
}

// ---------------- final layer ----------------
__global__ void __launch_bounds__(256) k_final(const unsigned short* __restrict__ agg,
                                               const float* __restrict__ wstk,
                                               const void* __restrict__ bias,
                                               void* __restrict__ out,
                                               const int* __restrict__ flags) {
    int f32 = flags[0];
    int node = (blockIdx.x * blockDim.x + threadIdx.x) >> 6;
    int lane = threadIdx.x & 63;
    if (node >= NN) return;
    float f0 = 0, f1 = 0, f2 = 0;
    const unsigned short* ar = agg + (size_t)node * 768;
#pragma unroll
    for (int it = 0; it < 6; it++) {
        int m = it * 128 + 2 * lane;
        unsigned int w = *(const unsigned int*)(ar + m);
        float a0 = lo2f(w);
        float a1 = hi2f(w);
        f0 += a0 * wstk[m * 3 + 0] + a1 * wstk[m * 3 + 3];
        f1 += a0 * wstk[m * 3 + 1] + a1 * wstk[m * 3 + 4];
        f2 += a0 * wstk[m * 3 + 2] + a1 * wstk[m * 3 + 5];
    }
#pragma unroll
    for (int off = 32; off > 0; off >>= 1) {
        f0 += __shfl_down(f0, off, 64);
        f1 += __shfl_down(f1, off, 64);
        f2 += __shfl_down(f2, off, 64);
    }
    if (lane == 0) {
        float r0 = f0 + ldf(bias, 0, f32);
        float r1 = f1 + ldf(bias, 1, f32);
        float r2 = f2 + ldf(bias, 2, f32);
        if (f32) {
            float* o = (float*)out;
            o[(size_t)node * 3 + 0] = r0;
            o[(size_t)node * 3 + 1] = r1;
            o[(size_t)node * 3 + 2] = r2;
        } else {
            __hip_bfloat16* o = (__hip_bfloat16*)out;
            o[(size_t)node * 3 + 0] = __float2bfloat16(r0);
            o[(size_t)node * 3 + 1] = __float2bfloat16(r1);
            o[(size_t)node * 3 + 2] = __float2bfloat16(r2);
        }
    }
}

extern "C" void kernel_launch(void* const* d_in, const int* in_sizes, int n_in,
                              void* d_out, int out_size, void* d_ws, size_t ws_size,
                              hipStream_t stream) {
    (void)in_sizes; (void)n_in; (void)out_size; (void)ws_size;
    const void* pos = d_in[0];
    const void* nrm = d_in[1];
    const int* ei = (const int*)d_in[2];
    const void* W[4] = {d_in[3], d_in[7], d_in[11], d_in[15]};
    const void* U[4] = {d_in[4], d_in[8], d_in[12], d_in[16]};
    const void* Cc[4] = {d_in[5], d_in[9], d_in[13], d_in[17]};
    const void* Bb[4] = {d_in[6], d_in[10], d_in[14], d_in[18]};

    char* wp = (char*)d_ws;
    auto alloc = [&](size_t b) { void* r = (void*)wp; wp += (b + 255) & ~(size_t)255; return r; };
    unsigned short* xA  = (unsigned short*)alloc((size_t)NN * 128 * 2);
    unsigned short* xB  = (unsigned short*)alloc((size_t)NN * 128 * 2);
    unsigned short* x0b = (unsigned short*)alloc((size_t)NN * 8 * 2);
    float* p8     = (float*)alloc((size_t)NN * 8 * 4);
    int*   counts = (int*)alloc((size_t)NN * 4);
    int*   offs   = (int*)alloc((size_t)(NN + 1) * 4);
    int*   cntT   = (int*)alloc((size_t)NBK * SWG * 4);
    int*   base2  = (int*)alloc((size_t)(NBK * SWG + 1) * 4);
    int*   flags  = (int*)alloc(256);
    int*   ssrc   = (int*)alloc((size_t)NE * 4);
    unsigned int* ebuck = (unsigned int*)alloc((size_t)NE * 4);
    void*  aggv   = alloc((size_t)NN * 768 * 2);
    float* wstk1  = (float*)alloc((size_t)36 * 128 * 4);
    unsigned short* wt2 = (unsigned short*)alloc((size_t)128 * 768 * 2);
    unsigned short* wt3 = (unsigned short*)alloc((size_t)128 * 768 * 2);
    float* wstk4  = (float*)alloc((size_t)768 * 3 * 4);
    unsigned short* agg_h = (unsigned short*)aggv;
    float* agg_f = (float*)aggv;

    const int NB = (NN + 255) / 256;
    const int NWB = (NN * 64 + 255) / 256;      // 256-thread wave-per-node grids
    const int NWB128 = (NN * 64 + 127) / 128;   // 128-thread wave-per-node grid
    const int GB = (NN + 63) / 64;

    k_detect<<<1, 256, 0, stream>>>(pos, ei, flags);
    hipMemsetAsync(counts, 0, (size_t)NN * 4, stream);
    k_sortA<<<SWG, 256, 0, stream>>>(ei, counts, cntT, flags);
    k_scan2<<<2, 1024, 0, stream>>>(counts, offs, NN, cntT, base2, NBK * SWG);
    k_sortB<<<SWG, 256, 0, stream>>>(ei, base2, ebuck, flags);
    k_sortC<<<NBK, 256, 0, stream>>>(ebuck, base2, offs, ssrc);
    k_build_x0<<<NB, 256, 0, stream>>>(pos, nrm, x0b, flags);
    k_repack_all<<<(203520 + 255) / 256, 256, 0, stream>>>(W[0], W[1], W[2], W[3],
                                                           wstk1, wt2, wt3, wstk4, flags);

    // ---- layer 1: 6 -> 128, relu ----
    k_compute_p6<<<NWB, 256, 0, stream>>>(x0b, U[0], p8, flags);
    k_agg6<<<NWB, 256, 0, stream>>>(x0b, p8, Cc[0], ssrc, offs, agg_f, flags);
    k_gemm_f32<<<GB, 256, 0, stream>>>(agg_f, wstk1, Bb[0], xA, NN, 36, 1, flags);

    // ---- layer 2: 128 -> 128, relu ----
    k_compute_p128<<<NWB, 256, 0, stream>>>(xA, U[1], p8, flags);
    k_agg128<<<NWB128, 128, 0, stream>>>(xA, p8, Cc[1], ssrc, offs, agg_h, flags);
    k_gemm_mfma<<<GB, 256, 0, stream>>>(agg_h, wt2, Bb[1], xB, NN, 1, flags);

    // ---- layer 3: 128 -> 128, relu ----
    k_compute_p128<<<NWB, 256, 0, stream>>>(xB, U[2], p8, flags);
    k_agg128<<<NWB128, 128, 0, stream>>>(xB, p8, Cc[2], ssrc, offs, agg_h, flags);
    k_gemm_mfma<<<GB, 256, 0, stream>>>(agg_h, wt3, Bb[2], xA, NN, 1, flags);

    // ---- layer 4: 128 -> 3 ----
    k_compute_p128<<<NWB, 256, 0, stream>>>(xA, U[3], p8, flags);
    k_agg128<<<NWB128, 128, 0, stream>>>(xA, p8, Cc[3], ssrc, offs, agg_h, flags);
    k_final<<<NWB, 256, 0, stream>>>(agg_h, wstk4, Bb[3], d_out, flags);
}

// Round 7
// 794.661 us; speedup vs baseline: 1.0956x; 1.0637x over previous
//
#include <hip/hip_runtime.h>
#include <hip/hip_bf16.h>

// FeaStConv x4 on MI355X.
//  (1) (xj-xi)@u = p[src]-p[dst] with p = x@u per node (p padded to [N,8]).
//  (2) out_i = sum_h (sum_j q_h x_j) @ W_h  -> gather x_j into per-head
//      aggregates Agg[N, H*Cin], then ONE dense GEMM per layer (MFMA bf16).
// Round 7: k_agg128 VALU diet — DMA offsets via v_readlane (no LDS round
// trip), q stored fp32 in LDS (no per-edge bf16 unpack), f32x2 accumulators
// -> v_pk_fma_f32 (12 fmac -> 6 pk_fma). k_agg6 rewritten with DMA staging
// (was latency-serialized global scalar loads, ~110 us hidden).

#define HH 6
constexpr int NN = 50000;
constexpr int NE = 1600000;
constexpr int NBK = 196;           // buckets: dst>>8, covers 50176 nodes
constexpr int SWG = 256;           // sort workgroups
constexpr int EPW = NE / SWG;      // 6250 edges per sort wg

typedef __attribute__((ext_vector_type(8))) short bf16x8;
typedef __attribute__((ext_vector_type(4))) float f32x4;
typedef __attribute__((ext_vector_type(2))) float f32x2;

static __device__ __forceinline__ float b2f(__hip_bfloat16 v) { return __bfloat162float(v); }
static __device__ __forceinline__ float u2f(unsigned short u) {
    return __uint_as_float(((unsigned int)u) << 16);
}
static __device__ __forceinline__ unsigned short f2bu(float v) {
    __hip_bfloat16 b = __float2bfloat16(v);
    return *reinterpret_cast<unsigned short*>(&b);
}
static __device__ __forceinline__ float lo2f(unsigned int w) {
    return __uint_as_float(w << 16);
}
static __device__ __forceinline__ float hi2f(unsigned int w) {
    return __uint_as_float(w & 0xffff0000u);
}
static __device__ __forceinline__ unsigned int pk2(float lo, float hi) {
    return ((unsigned int)f2bu(hi) << 16) | (unsigned int)f2bu(lo);
}
static __device__ __forceinline__ float ldf(const void* p, int i, int f32) {
    return f32 ? ((const float*)p)[i] : b2f(((const __hip_bfloat16*)p)[i]);
}
static __device__ __forceinline__ int ldi(const int* e32, int i, int i64) {
    return i64 ? e32[2 * i] : e32[i];
}
// async global->LDS: each lane copies 4B; lane i lands at ldst + i*4
static __device__ __forceinline__ void dma4(const void* g, void* l) {
    __builtin_amdgcn_global_load_lds(
        (const __attribute__((address_space(1))) void*)g,
        (__attribute__((address_space(3))) void*)l, 4, 0, 0);
}

// ---------------- dtype detection ----------------
__global__ void k_detect(const void* pos, const void* ei, int* flags) {
    __shared__ float smax[256];
    __shared__ int anynz;
    int t = threadIdx.x;
    if (t == 0) anynz = 0;
    const __hip_bfloat16* pb = (const __hip_bfloat16*)pos;
    float m = 0.f;
    for (int i = t; i < 2048; i += 256) {
        float v = fabsf(b2f(pb[i]));
        if (v != v) v = 1e30f;
        m = fmaxf(m, v);
    }
    smax[t] = m;
    __syncthreads();
    for (int s = 128; s > 0; s >>= 1) {
        if (t < s) smax[t] = fmaxf(smax[t], smax[t + s]);
        __syncthreads();
    }
    const int* e32 = (const int*)ei;
    if (t < 128 && e32[2 * t + 1] != 0) anynz = 1;
    __syncthreads();
    if (t == 0) {
        flags[0] = (smax[0] > 1e6f) ? 1 : 0;
        flags[1] = anynz ? 0 : 1;
    }
}

// ---------------- input assembly: x0 bf16 [N,8] (pads 0) ----------------
__global__ void k_build_x0(const void* __restrict__ pos, const void* __restrict__ nrm,
                           unsigned short* __restrict__ x0b, const int* __restrict__ flags) {
    int f32 = flags[0];
    int i = blockIdx.x * blockDim.x + threadIdx.x;
    if (i >= NN) return;
#pragma unroll
    for (int j = 0; j < 3; j++) {
        x0b[i * 8 + j]     = f32 ? f2bu(((const float*)pos)[i * 3 + j])
                                 : ((const unsigned short*)pos)[i * 3 + j];
        x0b[i * 8 + 3 + j] = f32 ? f2bu(((const float*)nrm)[i * 3 + j])
                                 : ((const unsigned short*)nrm)[i * 3 + j];
    }
    x0b[i * 8 + 6] = 0;
    x0b[i * 8 + 7] = 0;
}

// ---------------- CSR build: two-level counting sort ----------------
__global__ void __launch_bounds__(256) k_sortA(const int* __restrict__ ei,
                                               int* __restrict__ counts,
                                               int* __restrict__ cntT,
                                               const int* __restrict__ flags) {
    __shared__ int hist[NBK];
    int i64 = flags[1];
    int t = threadIdx.x, w = blockIdx.x;
    for (int b = t; b < NBK; b += 256) hist[b] = 0;
    __syncthreads();
    int start = w * EPW, end = start + EPW;
    for (int e = start + t; e < end; e += 256) {
        int d = ldi(ei, NE + e, i64);
        atomicAdd(&counts[d], 1);
        atomicAdd(&hist[d >> 8], 1);
    }
    __syncthreads();
    for (int b = t; b < NBK; b += 256) cntT[b * SWG + w] = hist[b];
}

__global__ void __launch_bounds__(1024) k_scan2(const int* __restrict__ a0, int* __restrict__ o0,
                                                int n0, const int* __restrict__ a1,
                                                int* __restrict__ o1, int n1) {
    const int* a = (blockIdx.x == 0) ? a0 : a1;
    int* o = (blockIdx.x == 0) ? o0 : o1;
    int n = (blockIdx.x == 0) ? n0 : n1;
    __shared__ int wsum[16];
    __shared__ int s_running;
    int t = threadIdx.x;
    int lane = t & 63, wid = t >> 6;
    if (t == 0) s_running = 0;
    __syncthreads();
    for (int base = 0; base < n; base += 1024) {
        int v = (base + t < n) ? a[base + t] : 0;
        int incl = v;
#pragma unroll
        for (int off = 1; off < 64; off <<= 1) {
            int nb = __shfl_up(incl, off, 64);
            if (lane >= off) incl += nb;
        }
        if (lane == 63) wsum[wid] = incl;
        __syncthreads();
        int wprefix = 0, total = 0;
#pragma unroll
        for (int wi = 0; wi < 16; wi++) {
            int s = wsum[wi];
            if (wi < wid) wprefix += s;
            total += s;
        }
        if (base + t < n) o[base + t] = s_running + wprefix + (incl - v);
        __syncthreads();
        if (t == 0) s_running += total;
        __syncthreads();
    }
    if (t == 0) o[n] = s_running;
}

__global__ void __launch_bounds__(256) k_sortB(const int* __restrict__ ei,
                                               const int* __restrict__ base2,
                                               unsigned int* __restrict__ ebuck,
                                               const int* __restrict__ flags) {
    __shared__ int cur[NBK];
    int i64 = flags[1];
    int t = threadIdx.x, w = blockIdx.x;
    for (int b = t; b < NBK; b += 256) cur[b] = base2[b * SWG + w];
    __syncthreads();
    int start = w * EPW, end = start + EPW;
    for (int e = start + t; e < end; e += 256) {
        int s = ldi(ei, e, i64), d = ldi(ei, NE + e, i64);
        int slot = atomicAdd(&cur[d >> 8], 1);
        ebuck[slot] = (unsigned int)s | ((unsigned int)(d & 255) << 16);
    }
}

__global__ void __launch_bounds__(256) k_sortC(const unsigned int* __restrict__ ebuck,
                                               const int* __restrict__ base2,
                                               const int* __restrict__ offs,
                                               int* __restrict__ ssrc) {
    __shared__ int cur[256];
    int t = threadIdx.x, b = blockIdx.x;
    int gn = b * 256 + t;
    cur[t] = (gn < NN) ? offs[gn] : NE;
    __syncthreads();
    int bs = base2[b * SWG], be = base2[(b + 1) * SWG];
    for (int e = bs + t; e < be; e += 256) {
        unsigned int rec = ebuck[e];
        int slot = atomicAdd(&cur[(rec >> 16) & 255], 1);
        ssrc[slot] = (int)(rec & 0xffffu);
    }
}

// ---------------- p = x @ u  ->  p8 [N,8] fp32 (h<6 valid) ----------------
__global__ void __launch_bounds__(256) k_compute_p6(const unsigned short* __restrict__ x0b,
                                                    const void* __restrict__ u,
                                                    float* __restrict__ p8,
                                                    const int* __restrict__ flags) {
    int f32 = flags[0];
    int wave = (blockIdx.x * blockDim.x + threadIdx.x) >> 6;
    int lane = threadIdx.x & 63;
    if (wave >= NN) return;
    float acc[HH] = {0, 0, 0, 0, 0, 0};
    if (lane < 6) {
        float xv = u2f(x0b[(size_t)wave * 8 + lane]);
#pragma unroll
        for (int h = 0; h < HH; h++) acc[h] = xv * ldf(u, lane * HH + h, f32);
    }
#pragma unroll
    for (int off = 4; off > 0; off >>= 1) {
#pragma unroll
        for (int h = 0; h < HH; h++) acc[h] += __shfl_down(acc[h], off, 64);
    }
    if (lane == 0) {
#pragma unroll
        for (int h = 0; h < HH; h++) p8[(size_t)wave * 8 + h] = acc[h];
    }
}

__global__ void __launch_bounds__(256) k_compute_p128(const unsigned short* __restrict__ x,
                                                      const void* __restrict__ u,
                                                      float* __restrict__ p8,
                                                      const int* __restrict__ flags) {
    int f32 = flags[0];
    int wave = (blockIdx.x * blockDim.x + threadIdx.x) >> 6;
    int lane = threadIdx.x & 63;
    if (wave >= NN) return;
    unsigned int w = *(const unsigned int*)(x + (size_t)wave * 128 + 2 * lane);
    float x0 = lo2f(w);
    float x1 = hi2f(w);
    float acc[HH];
#pragma unroll
    for (int h = 0; h < HH; h++)
        acc[h] = x0 * ldf(u, (2 * lane) * HH + h, f32) + x1 * ldf(u, (2 * lane + 1) * HH + h, f32);
#pragma unroll
    for (int off = 32; off > 0; off >>= 1) {
#pragma unroll
        for (int h = 0; h < HH; h++) acc[h] += __shfl_down(acc[h], off, 64);
    }
    if (lane == 0) {
#pragma unroll
        for (int h = 0; h < HH; h++) p8[(size_t)wave * 8 + h] = acc[h];
    }
}

// ---------------- fused softmax + aggregation, CIN=128 ----------------
// 128 threads = 2 waves, wave per node. Per 32-edge chunk: phase A (lanes
// 0-31) computes fp32 q -> LDS; 32 row-DMAs with v_readlane offsets; phase B
// f32x2 accumulate (v_pk_fma_f32) from LDS.
__global__ void __launch_bounds__(128) k_agg128(const unsigned short* __restrict__ xb,
                                                const float* __restrict__ p8,
                                                const void* __restrict__ cvec,
                                                const int* __restrict__ ssrc,
                                                const int* __restrict__ offs,
                                                unsigned short* __restrict__ agg,
                                                const int* __restrict__ flags) {
    __shared__ unsigned short stage[2][32 * 128];   // 16 KB: 32 staged rows/wave
    __shared__ float qsf[2][32][8];                 // 2 KB: fp32 q[6] per edge
    int f32 = flags[0];
    int wid = threadIdx.x >> 6, lane = threadIdx.x & 63;
    int node = (blockIdx.x * blockDim.x + threadIdx.x) >> 6;
    node = __builtin_amdgcn_readfirstlane(node);
    if (node >= NN) return;
    int s0 = offs[node], s1 = offs[node + 1];
    int deg = s1 - s0;
    float scale = 1.0f / (float)(deg > 0 ? deg : 1);
    const float* pn = p8 + (size_t)node * 8;
    float pd[HH];
#pragma unroll
    for (int h = 0; h < HH; h++) pd[h] = pn[h] - ldf(cvec, h, f32);

    f32x2 a[HH] = {};
    for (int base = s0; base < s1; base += 32) {
        int cnt = (s1 - base < 32) ? (s1 - base) : 32;
        // ---- phase A: lanes 0..31 = edges; fp32 q -> LDS ----
        unsigned int rowElem = 0;
        if (lane < 32) {
            int e = base + lane;
            float q0 = 0, q1 = 0, q2 = 0, q3 = 0, q4 = 0, q5 = 0;
            if (e < s1) {
                int j = ssrc[e];
                const float* pj = p8 + (size_t)j * 8;
                float4 pa = *(const float4*)pj;
                float2 pb = *(const float2*)(pj + 4);
                float t0 = pa.x - pd[0], t1 = pa.y - pd[1], t2 = pa.z - pd[2];
                float t3 = pa.w - pd[3], t4 = pb.x - pd[4], t5 = pb.y - pd[5];
                float mx = fmaxf(fmaxf(fmaxf(t0, t1), fmaxf(t2, t3)), fmaxf(t4, t5));
                q0 = __expf(t0 - mx); q1 = __expf(t1 - mx); q2 = __expf(t2 - mx);
                q3 = __expf(t3 - mx); q4 = __expf(t4 - mx); q5 = __expf(t5 - mx);
                float inv = 1.0f / (q0 + q1 + q2 + q3 + q4 + q5);
                q0 *= inv; q1 *= inv; q2 *= inv; q3 *= inv; q4 *= inv; q5 *= inv;
                rowElem = (unsigned int)j * 128u;
            }
            float4 qa = {q0, q1, q2, q3};
            float2 qb = {q4, q5};
            *(float4*)&qsf[wid][lane][0] = qa;
            *(float2*)&qsf[wid][lane][4] = qb;
        }
        __builtin_amdgcn_sched_barrier(0);
        // ---- issue row DMAs; offsets from lane registers via readlane ----
#pragma unroll
        for (int s = 0; s < 32; s++) {
            if (s < cnt) {
                unsigned int off = (unsigned int)__builtin_amdgcn_readlane((int)rowElem, s);
                dma4(xb + off + 2 * lane, &stage[wid][s * 128]);
            }
        }
        __builtin_amdgcn_s_waitcnt(0x0f70);          // vmcnt(0) only
        __builtin_amdgcn_sched_barrier(0);
        // ---- phase B: lane = channel pair; pure LDS, pk_fma ----
        for (int s = 0; s < cnt; s++) {
            float4 qa = *(const float4*)&qsf[wid][s][0];   // broadcast
            float2 qb = *(const float2*)&qsf[wid][s][4];
            unsigned int xw = *(const unsigned int*)&stage[wid][s * 128 + 2 * lane];
            f32x2 xx;
            xx.x = lo2f(xw);
            xx.y = hi2f(xw);
            f32x2 q0 = qa.x, q1 = qa.y, q2 = qa.z, q3 = qa.w, q4 = qb.x, q5 = qb.y;
            a[0] = __builtin_elementwise_fma(q0, xx, a[0]);
            a[1] = __builtin_elementwise_fma(q1, xx, a[1]);
            a[2] = __builtin_elementwise_fma(q2, xx, a[2]);
            a[3] = __builtin_elementwise_fma(q3, xx, a[3]);
            a[4] = __builtin_elementwise_fma(q4, xx, a[4]);
            a[5] = __builtin_elementwise_fma(q5, xx, a[5]);
        }
        __builtin_amdgcn_sched_barrier(0);           // keep next DMAs after reads
    }
    unsigned short* ar = agg + (size_t)node * 768;
#pragma unroll
    for (int h = 0; h < HH; h++) {
        *(unsigned int*)(ar + h * 128 + 2 * lane) = pk2(a[h].x * scale, a[h].y * scale);
    }
}

// ---------------- fused softmax + aggregation, CIN=6 ----------------
// 256 threads = 4 waves, wave per node. Per 64-edge chunk: phase A computes
// fp32 q + row byte offset -> LDS; 4 DMAs stage 64 rows x 16 B (lane i ->
// row i>>2, dword i&3); phase B from LDS, lanes 0..35 = (h,k).
__global__ void __launch_bounds__(256) k_agg6(const unsigned short* __restrict__ xb,
                                              const float* __restrict__ p8,
                                              const void* __restrict__ cvec,
                                              const int* __restrict__ ssrc,
                                              const int* __restrict__ offs,
                                              float* __restrict__ agg,
                                              const int* __restrict__ flags) {
    __shared__ unsigned short stage6[4][64 * 8];     // 4 KB: 64 rows x 16 B
    __shared__ float qsf[4][64][8];                  // 8 KB: q[6] + rowbyte bits
    int f32 = flags[0];
    int wid = threadIdx.x >> 6, lane = threadIdx.x & 63;
    int node = (blockIdx.x * blockDim.x + threadIdx.x) >> 6;
    node = __builtin_amdgcn_readfirstlane(node);
    if (node >= NN) return;
    int s0 = offs[node], s1 = offs[node + 1];
    int deg = s1 - s0;
    float scale = 1.0f / (float)(deg > 0 ? deg : 1);
    const float* pn = p8 + (size_t)node * 8;
    float pd[HH];
#pragma unroll
    for (int h = 0; h < HH; h++) pd[h] = pn[h] - ldf(cvec, h, f32);

    float acc6 = 0.f;
    int hh6 = lane / 6, kk6 = lane - hh6 * 6;
    const char* xbase = (const char*)xb;
    for (int base = s0; base < s1; base += 64) {
        int cnt = (s1 - base < 64) ? (s1 - base) : 64;
        // ---- phase A: lane = edge ----
        {
            int e = base + lane;
            float q0 = 0, q1 = 0, q2 = 0, q3 = 0, q4 = 0, q5 = 0;
            unsigned int rowByte = 0;
            if (e < s1) {
                int j = ssrc[e];
                const float* pj = p8 + (size_t)j * 8;
                float4 pa = *(const float4*)pj;
                float2 pb = *(const float2*)(pj + 4);
                float t0 = pa.x - pd[0], t1 = pa.y - pd[1], t2 = pa.z - pd[2];
                float t3 = pa.w - pd[3], t4 = pb.x - pd[4], t5 = pb.y - pd[5];
                float mx = fmaxf(fmaxf(fmaxf(t0, t1), fmaxf(t2, t3)), fmaxf(t4, t5));
                q0 = __expf(t0 - mx); q1 = __expf(t1 - mx); q2 = __expf(t2 - mx);
                q3 = __expf(t3 - mx); q4 = __expf(t4 - mx); q5 = __expf(t5 - mx);
                float inv = 1.0f / (q0 + q1 + q2 + q3 + q4 + q5);
                q0 *= inv; q1 *= inv; q2 *= inv; q3 *= inv; q4 *= inv; q5 *= inv;
                rowByte = (unsigned int)j * 16u;     // row = 8 bf16 = 16 B
            }
            float4 qa = {q0, q1, q2, q3};
            float4 qb = {q4, q5, __uint_as_float(rowByte), 0.f};
            *(float4*)&qsf[wid][lane][0] = qa;
            *(float4*)&qsf[wid][lane][4] = qb;
        }
        __builtin_amdgcn_sched_barrier(0);
        // ---- 4 DMAs stage 64 rows (lane i: row t*16 + (i>>2), dword i&3) ----
#pragma unroll
        for (int t = 0; t < 4; t++) {
            int r = t * 16 + (lane >> 2);
            unsigned int rb = __float_as_uint(qsf[wid][r][6]);
            dma4(xbase + rb + (lane & 3) * 4, &stage6[wid][t * 128]);
        }
        __builtin_amdgcn_s_waitcnt(0x0f70);          // vmcnt(0) only
        __builtin_amdgcn_sched_barrier(0);
        // ---- phase B: lanes 0..35 = (h,k) ----
        if (lane < 36) {
            for (int s = 0; s < cnt; s++) {
                float qh = qsf[wid][s][hh6];
                float xv = u2f(stage6[wid][s * 8 + kk6]);
                acc6 = fmaf(qh, xv, acc6);
            }
        }
        __builtin_amdgcn_sched_barrier(0);
    }
    if (lane < 36) agg[(size_t)node * 36 + lane] = acc6 * scale;
}

// ---------------- fused weight repacks ----------------
__global__ void k_repack_all(const void* __restrict__ W1, const void* __restrict__ W2,
                             const void* __restrict__ W3, const void* __restrict__ W4,
                             float* __restrict__ wstk1, unsigned short* __restrict__ wt2,
                             unsigned short* __restrict__ wt3, float* __restrict__ wstk4,
                             const int* __restrict__ flags) {
    int f32 = flags[0];
    int idx = blockIdx.x * blockDim.x + threadIdx.x;
    if (idx < 4608) {
        int f = idx & 127, m = idx >> 7;
        int h = m / 6, k = m - h * 6;
        wstk1[idx] = ldf(W1, k * 768 + h * 128 + f, f32);
        return;
    }
    idx -= 4608;
    if (idx < 98304) {
        int f = idx / 768, m = idx % 768;
        int h = m >> 7, kk = m & 127;
        wt2[idx] = f2bu(ldf(W2, kk * 768 + h * 128 + f, f32));
        return;
    }
    idx -= 98304;
    if (idx < 98304) {
        int f = idx / 768, m = idx % 768;
        int h = m >> 7, kk = m & 127;
        wt3[idx] = f2bu(ldf(W3, kk * 768 + h * 128 + f, f32));
        return;
    }
    idx -= 98304;
    if (idx < 2304) {
        int f = idx % 3, m = idx / 3;
        int h = m >> 7, k = m & 127;
        wstk4[idx] = ldf(W4, k * 18 + h * 3 + f, f32);
    }
}

// ---------------- layer-1 GEMM (fp32, K=36), writes bf16 x ----------------
__global__ void __launch_bounds__(256) k_gemm_f32(const float* __restrict__ A,
                                                  const float* __restrict__ B,
                                                  const void* __restrict__ bias,
                                                  unsigned short* __restrict__ C,
                                                  int M, int K, int relu,
                                                  const int* __restrict__ flags) {
    int f32 = flags[0];
    __shared__ float As[16][68];
    __shared__ float Bs[16][128];
    int tid = threadIdx.x;
    int tx = tid & 15;
    int ty = tid >> 4;
    int bm = blockIdx.x * 64;
    int arow = tid >> 2, ak = (tid & 3) * 4;
    int brow = tid >> 4, bcol = (tid & 15) * 8;
    float acc[4][8] = {};
    for (int k0 = 0; k0 < K; k0 += 16) {
        float4 av = {0, 0, 0, 0};
        int gr = bm + arow;
        if (gr < M && (k0 + ak) < K) av = *(const float4*)(A + (size_t)gr * K + k0 + ak);
        As[ak + 0][arow] = av.x;
        As[ak + 1][arow] = av.y;
        As[ak + 2][arow] = av.z;
        As[ak + 3][arow] = av.w;
        float4 bv0 = {0, 0, 0, 0}, bv1 = {0, 0, 0, 0};
        if ((k0 + brow) < K) {
            const float* bp = B + (size_t)(k0 + brow) * 128 + bcol;
            bv0 = *(const float4*)bp;
            bv1 = *(const float4*)(bp + 4);
        }
        *(float4*)&Bs[brow][bcol]     = bv0;
        *(float4*)&Bs[brow][bcol + 4] = bv1;
        __syncthreads();
#pragma unroll
        for (int kk = 0; kk < 16; kk++) {
            float a_[4], b_[8];
#pragma unroll
            for (int j = 0; j < 4; j++) a_[j] = As[kk][ty * 4 + j];
#pragma unroll
            for (int j = 0; j < 8; j++) b_[j] = Bs[kk][tx * 8 + j];
#pragma unroll
            for (int i = 0; i < 4; i++)
#pragma unroll
                for (int j = 0; j < 8; j++) acc[i][j] = fmaf(a_[i], b_[j], acc[i][j]);
        }
        __syncthreads();
    }
#pragma unroll
    for (int i = 0; i < 4; i++) {
        int row = bm + ty * 4 + i;
        if (row >= M) continue;
#pragma unroll
        for (int j = 0; j < 8; j++) {
            int col = tx * 8 + j;
            float v = acc[i][j] + ldf(bias, col, f32);
            if (relu) v = fmaxf(v, 0.f);
            C[(size_t)row * 128 + col] = f2bu(v);
        }
    }
}

// ---------------- MFMA GEMM: C[M,128] = A[M,768]bf16 @ Wt^T + bias, ReLU ----
__global__ void __launch_bounds__(256) k_gemm_mfma(const unsigned short* __restrict__ A,
                                                   const unsigned short* __restrict__ Bt,
                                                   const void* __restrict__ bias,
                                                   unsigned short* __restrict__ C,
                                                   int M, int relu,
                                                   const int* __restrict__ flags) {
    constexpr int K = 768, BK = 64;
    __shared__ unsigned short As[64][72];
    __shared__ unsigned short Bs[128][72];
    int f32 = flags[0];
    int tid = threadIdx.x;
    int lane = tid & 63, wid = tid >> 6;
    int wm = wid & 1, wn = wid >> 1;
    int bm = blockIdx.x * 64;
    int l15 = lane & 15, lq = lane >> 4;
    f32x4 acc[2][4] = {};

    for (int k0 = 0; k0 < K; k0 += BK) {
#pragma unroll
        for (int cc = 0; cc < 2; cc++) {
            int c = tid + cc * 256;
            int r = c >> 3, kc = (c & 7) * 8;
            bf16x8 av = {};
            int gr = bm + r;
            if (gr < M) av = *(const bf16x8*)(A + (size_t)gr * K + k0 + kc);
            *(bf16x8*)&As[r][kc] = av;
        }
#pragma unroll
        for (int cc = 0; cc < 4; cc++) {
            int c = tid + cc * 256;
            int n = c >> 3, kc = (c & 7) * 8;
            *(bf16x8*)&Bs[n][kc] = *(const bf16x8*)(Bt + (size_t)n * K + k0 + kc);
        }
        __syncthreads();
#pragma unroll
        for (int ks = 0; ks < BK; ks += 32) {
            int koff = ks + lq * 8;
            bf16x8 af[2], bfr[4];
#pragma unroll
            for (int tm = 0; tm < 2; tm++)
                af[tm] = *(const bf16x8*)&As[wm * 32 + tm * 16 + l15][koff];
#pragma unroll
            for (int tn = 0; tn < 4; tn++)
                bfr[tn] = *(const bf16x8*)&Bs[wn * 64 + tn * 16 + l15][koff];
#pragma unroll
            for (int tm = 0; tm < 2; tm++)
#pragma unroll
                for (int tn = 0; tn < 4; tn++)
                    acc[tm][tn] = __builtin_amdgcn_mfma_f32_16x16x32_bf16(
                        af[tm], bfr[tn], acc[tm][tn], 0, 0, 0);
        }
        __syncthreads();
    }
#pragma unroll
    for (int tm = 0; tm < 2; tm++) {
#pragma unroll
        for (int tn = 0; tn < 4; tn++) {
            int col = wn * 64 + tn * 16 + l15;
            float bv = ldf(bias, col, f32);
#pragma unroll
            for (int r = 0; r < 4; r++) {
                int row = bm + wm * 32 + tm * 16 + lq * 4 + r;
                if (row < M) {
                    float v = acc[tm][tn][r] + bv;
                    if (relu) v = fmaxf(v, 0.f);
                    C[(size_t)row * 128 + col] = f2bu(v);
                }
            }
        }
    }
}

// ---------------- final layer ----------------
__global__ void __launch_bounds__(256) k_final(const unsigned short* __restrict__ agg,
                                               const float* __restrict__ wstk,
                                               const void* __restrict__ bias,
                                               void* __restrict__ out,
                                               const int* __restrict__ flags) {
    int f32 = flags[0];
    int node = (blockIdx.x * blockDim.x + threadIdx.x) >> 6;
    int lane = threadIdx.x & 63;
    if (node >= NN) return;
    float f0 = 0, f1 = 0, f2 = 0;
    const unsigned short* ar = agg + (size_t)node * 768;
#pragma unroll
    for (int it = 0; it < 6; it++) {
        int m = it * 128 + 2 * lane;
        unsigned int w = *(const unsigned int*)(ar + m);
        float a0 = lo2f(w);
        float a1 = hi2f(w);
        f0 += a0 * wstk[m * 3 + 0] + a1 * wstk[m * 3 + 3];
        f1 += a0 * wstk[m * 3 + 1] + a1 * wstk[m * 3 + 4];
        f2 += a0 * wstk[m * 3 + 2] + a1 * wstk[m * 3 + 5];
    }
#pragma unroll
    for (int off = 32; off > 0; off >>= 1) {
        f0 += __shfl_down(f0, off, 64);
        f1 += __shfl_down(f1, off, 64);
        f2 += __shfl_down(f2, off, 64);
    }
    if (lane == 0) {
        float r0 = f0 + ldf(bias, 0, f32);
        float r1 = f1 + ldf(bias, 1, f32);
        float r2 = f2 + ldf(bias, 2, f32);
        if (f32) {
            float* o = (float*)out;
            o[(size_t)node * 3 + 0] = r0;
            o[(size_t)node * 3 + 1] = r1;
            o[(size_t)node * 3 + 2] = r2;
        } else {
            __hip_bfloat16* o = (__hip_bfloat16*)out;
            o[(size_t)node * 3 + 0] = __float2bfloat16(r0);
            o[(size_t)node * 3 + 1] = __float2bfloat16(r1);
            o[(size_t)node * 3 + 2] = __float2bfloat16(r2);
        }
    }
}

extern "C" void kernel_launch(void* const* d_in, const int* in_sizes, int n_in,
                              void* d_out, int out_size, void* d_ws, size_t ws_size,
                              hipStream_t stream) {
    (void)in_sizes; (void)n_in; (void)out_size; (void)ws_size;
    const void* pos = d_in[0];
    const void* nrm = d_in[1];
    const int* ei = (const int*)d_in[2];
    const void* W[4] = {d_in[3], d_in[7], d_in[11], d_in[15]};
    const void* U[4] = {d_in[4], d_in[8], d_in[12], d_in[16]};
    const void* Cc[4] = {d_in[5], d_in[9], d_in[13], d_in[17]};
    const void* Bb[4] = {d_in[6], d_in[10], d_in[14], d_in[18]};

    char* wp = (char*)d_ws;
    auto alloc = [&](size_t b) { void* r = (void*)wp; wp += (b + 255) & ~(size_t)255; return r; };
    unsigned short* xA  = (unsigned short*)alloc((size_t)NN * 128 * 2);
    unsigned short* xB  = (unsigned short*)alloc((size_t)NN * 128 * 2);
    unsigned short* x0b = (unsigned short*)alloc((size_t)NN * 8 * 2);
    float* p8     = (float*)alloc((size_t)NN * 8 * 4);
    int*   counts = (int*)alloc((size_t)NN * 4);
    int*   offs   = (int*)alloc((size_t)(NN + 1) * 4);
    int*   cntT   = (int*)alloc((size_t)NBK * SWG * 4);
    int*   base2  = (int*)alloc((size_t)(NBK * SWG + 1) * 4);
    int*   flags  = (int*)alloc(256);
    int*   ssrc   = (int*)alloc((size_t)NE * 4);
    unsigned int* ebuck = (unsigned int*)alloc((size_t)NE * 4);
    void*  aggv   = alloc((size_t)NN * 768 * 2);
    float* wstk1  = (float*)alloc((size_t)36 * 128 * 4);
    unsigned short* wt2 = (unsigned short*)alloc((size_t)128 * 768 * 2);
    unsigned short* wt3 = (unsigned short*)alloc((size_t)128 * 768 * 2);
    float* wstk4  = (float*)alloc((size_t)768 * 3 * 4);
    unsigned short* agg_h = (unsigned short*)aggv;
    float* agg_f = (float*)aggv;

    const int NB = (NN + 255) / 256;
    const int NWB = (NN * 64 + 255) / 256;      // 256-thread wave-per-node grids
    const int NWB128 = (NN * 64 + 127) / 128;   // 128-thread wave-per-node grid
    const int GB = (NN + 63) / 64;

    k_detect<<<1, 256, 0, stream>>>(pos, ei, flags);
    hipMemsetAsync(counts, 0, (size_t)NN * 4, stream);
    k_sortA<<<SWG, 256, 0, stream>>>(ei, counts, cntT, flags);
    k_scan2<<<2, 1024, 0, stream>>>(counts, offs, NN, cntT, base2, NBK * SWG);
    k_sortB<<<SWG, 256, 0, stream>>>(ei, base2, ebuck, flags);
    k_sortC<<<NBK, 256, 0, stream>>>(ebuck, base2, offs, ssrc);
    k_build_x0<<<NB, 256, 0, stream>>>(pos, nrm, x0b, flags);
    k_repack_all<<<(203520 + 255) / 256, 256, 0, stream>>>(W[0], W[1], W[2], W[3],
                                                           wstk1, wt2, wt3, wstk4, flags);

    // ---- layer 1: 6 -> 128, relu ----
    k_compute_p6<<<NWB, 256, 0, stream>>>(x0b, U[0], p8, flags);
    k_agg6<<<NWB, 256, 0, stream>>>(x0b, p8, Cc[0], ssrc, offs, agg_f, flags);
    k_gemm_f32<<<GB, 256, 0, stream>>>(agg_f, wstk1, Bb[0], xA, NN, 36, 1, flags);

    // ---- layer 2: 128 -> 128, relu ----
    k_compute_p128<<<NWB, 256, 0, stream>>>(xA, U[1], p8, flags);
    k_agg128<<<NWB128, 128, 0, stream>>>(xA, p8, Cc[1], ssrc, offs, agg_h, flags);
    k_gemm_mfma<<<GB, 256, 0, stream>>>(agg_h, wt2, Bb[1], xB, NN, 1, flags);

    // ---- layer 3: 128 -> 128, relu ----
    k_compute_p128<<<NWB, 256, 0, stream>>>(xB, U[2], p8, flags);
    k_agg128<<<NWB128, 128, 0, stream>>>(xB, p8, Cc[2], ssrc, offs, agg_h, flags);
    k_gemm_mfma<<<GB, 256, 0, stream>>>(agg_h, wt3, Bb[2], xA, NN, 1, flags);

    // ---- layer 4: 128 -> 3 ----
    k_compute_p128<<<NWB, 256, 0, stream>>>(xA, U[3], p8, flags);
    k_agg128<<<NWB128, 128, 0, stream>>>(xA, p8, Cc[3], ssrc, offs, agg_h, flags);
    k_final<<<NWB, 256, 0, stream>>>(agg_h, wstk4, Bb[3], d_out, flags);
}

// Round 8
// 794.144 us; speedup vs baseline: 1.0964x; 1.0007x over previous
//
#include <hip/hip_runtime.h>
#include <hip/hip_bf16.h>

// FeaStConv x4 on MI355X.
//  (1) (xj-xi)@u = p[src]-p[dst] with p = x@u per node (p padded to [N,8]).
//  (2) out_i = sum_h (sum_j q_h x_j) @ W_h  -> gather x_j into per-head
//      aggregates Agg[N, H*Cin], then ONE dense GEMM per layer (MFMA bf16).
// Round 8: k_agg128 is LDS-FREE. r7 accounting showed the LDS pipe (per-CU,
// shared by 4 SIMDs) was the bottleneck (~32 LDS-cyc/edge ~= 83 us). Now:
// chunk=64 edges, phase A keeps q0..q5+rowElem in lane registers; phase B
// broadcasts them via v_readlane (VALU pipe, 4x aggregate width of LDS) and
// gathers x with saddr-form global_load_dword, 8 loads in flight. Tail
// zero-padded to x8. Zero LDS -> full occupancy, no waitcnt choreography.

#define HH 6
constexpr int NN = 50000;
constexpr int NE = 1600000;
constexpr int NBK = 196;           // buckets: dst>>8, covers 50176 nodes
constexpr int SWG = 256;           // sort workgroups
constexpr int EPW = NE / SWG;      // 6250 edges per sort wg

typedef __attribute__((ext_vector_type(8))) short bf16x8;
typedef __attribute__((ext_vector_type(4))) float f32x4;
typedef __attribute__((ext_vector_type(2))) float f32x2;

static __device__ __forceinline__ float b2f(__hip_bfloat16 v) { return __bfloat162float(v); }
static __device__ __forceinline__ float u2f(unsigned short u) {
    return __uint_as_float(((unsigned int)u) << 16);
}
static __device__ __forceinline__ unsigned short f2bu(float v) {
    __hip_bfloat16 b = __float2bfloat16(v);
    return *reinterpret_cast<unsigned short*>(&b);
}
static __device__ __forceinline__ float lo2f(unsigned int w) {
    return __uint_as_float(w << 16);
}
static __device__ __forceinline__ float hi2f(unsigned int w) {
    return __uint_as_float(w & 0xffff0000u);
}
static __device__ __forceinline__ unsigned int pk2(float lo, float hi) {
    return ((unsigned int)f2bu(hi) << 16) | (unsigned int)f2bu(lo);
}
static __device__ __forceinline__ float ldf(const void* p, int i, int f32) {
    return f32 ? ((const float*)p)[i] : b2f(((const __hip_bfloat16*)p)[i]);
}
static __device__ __forceinline__ int ldi(const int* e32, int i, int i64) {
    return i64 ? e32[2 * i] : e32[i];
}
static __device__ __forceinline__ float rlf(float v, int s) {
    return __int_as_float(__builtin_amdgcn_readlane(__float_as_int(v), s));
}
// async global->LDS: each lane copies 4B; lane i lands at ldst + i*4
static __device__ __forceinline__ void dma4(const void* g, void* l) {
    __builtin_amdgcn_global_load_lds(
        (const __attribute__((address_space(1))) void*)g,
        (__attribute__((address_space(3))) void*)l, 4, 0, 0);
}

// ---------------- dtype detection ----------------
__global__ void k_detect(const void* pos, const void* ei, int* flags) {
    __shared__ float smax[256];
    __shared__ int anynz;
    int t = threadIdx.x;
    if (t == 0) anynz = 0;
    const __hip_bfloat16* pb = (const __hip_bfloat16*)pos;
    float m = 0.f;
    for (int i = t; i < 2048; i += 256) {
        float v = fabsf(b2f(pb[i]));
        if (v != v) v = 1e30f;
        m = fmaxf(m, v);
    }
    smax[t] = m;
    __syncthreads();
    for (int s = 128; s > 0; s >>= 1) {
        if (t < s) smax[t] = fmaxf(smax[t], smax[t + s]);
        __syncthreads();
    }
    const int* e32 = (const int*)ei;
    if (t < 128 && e32[2 * t + 1] != 0) anynz = 1;
    __syncthreads();
    if (t == 0) {
        flags[0] = (smax[0] > 1e6f) ? 1 : 0;
        flags[1] = anynz ? 0 : 1;
    }
}

// ---------------- input assembly: x0 bf16 [N,8] (pads 0) ----------------
__global__ void k_build_x0(const void* __restrict__ pos, const void* __restrict__ nrm,
                           unsigned short* __restrict__ x0b, const int* __restrict__ flags) {
    int f32 = flags[0];
    int i = blockIdx.x * blockDim.x + threadIdx.x;
    if (i >= NN) return;
#pragma unroll
    for (int j = 0; j < 3; j++) {
        x0b[i * 8 + j]     = f32 ? f2bu(((const float*)pos)[i * 3 + j])
                                 : ((const unsigned short*)pos)[i * 3 + j];
        x0b[i * 8 + 3 + j] = f32 ? f2bu(((const float*)nrm)[i * 3 + j])
                                 : ((const unsigned short*)nrm)[i * 3 + j];
    }
    x0b[i * 8 + 6] = 0;
    x0b[i * 8 + 7] = 0;
}

// ---------------- CSR build: two-level counting sort ----------------
__global__ void __launch_bounds__(256) k_sortA(const int* __restrict__ ei,
                                               int* __restrict__ counts,
                                               int* __restrict__ cntT,
                                               const int* __restrict__ flags) {
    __shared__ int hist[NBK];
    int i64 = flags[1];
    int t = threadIdx.x, w = blockIdx.x;
    for (int b = t; b < NBK; b += 256) hist[b] = 0;
    __syncthreads();
    int start = w * EPW, end = start + EPW;
    for (int e = start + t; e < end; e += 256) {
        int d = ldi(ei, NE + e, i64);
        atomicAdd(&counts[d], 1);
        atomicAdd(&hist[d >> 8], 1);
    }
    __syncthreads();
    for (int b = t; b < NBK; b += 256) cntT[b * SWG + w] = hist[b];
}

__global__ void __launch_bounds__(1024) k_scan2(const int* __restrict__ a0, int* __restrict__ o0,
                                                int n0, const int* __restrict__ a1,
                                                int* __restrict__ o1, int n1) {
    const int* a = (blockIdx.x == 0) ? a0 : a1;
    int* o = (blockIdx.x == 0) ? o0 : o1;
    int n = (blockIdx.x == 0) ? n0 : n1;
    __shared__ int wsum[16];
    __shared__ int s_running;
    int t = threadIdx.x;
    int lane = t & 63, wid = t >> 6;
    if (t == 0) s_running = 0;
    __syncthreads();
    for (int base = 0; base < n; base += 1024) {
        int v = (base + t < n) ? a[base + t] : 0;
        int incl = v;
#pragma unroll
        for (int off = 1; off < 64; off <<= 1) {
            int nb = __shfl_up(incl, off, 64);
            if (lane >= off) incl += nb;
        }
        if (lane == 63) wsum[wid] = incl;
        __syncthreads();
        int wprefix = 0, total = 0;
#pragma unroll
        for (int wi = 0; wi < 16; wi++) {
            int s = wsum[wi];
            if (wi < wid) wprefix += s;
            total += s;
        }
        if (base + t < n) o[base + t] = s_running + wprefix + (incl - v);
        __syncthreads();
        if (t == 0) s_running += total;
        __syncthreads();
    }
    if (t == 0) o[n] = s_running;
}

__global__ void __launch_bounds__(256) k_sortB(const int* __restrict__ ei,
                                               const int* __restrict__ base2,
                                               unsigned int* __restrict__ ebuck,
                                               const int* __restrict__ flags) {
    __shared__ int cur[NBK];
    int i64 = flags[1];
    int t = threadIdx.x, w = blockIdx.x;
    for (int b = t; b < NBK; b += 256) cur[b] = base2[b * SWG + w];
    __syncthreads();
    int start = w * EPW, end = start + EPW;
    for (int e = start + t; e < end; e += 256) {
        int s = ldi(ei, e, i64), d = ldi(ei, NE + e, i64);
        int slot = atomicAdd(&cur[d >> 8], 1);
        ebuck[slot] = (unsigned int)s | ((unsigned int)(d & 255) << 16);
    }
}

__global__ void __launch_bounds__(256) k_sortC(const unsigned int* __restrict__ ebuck,
                                               const int* __restrict__ base2,
                                               const int* __restrict__ offs,
                                               int* __restrict__ ssrc) {
    __shared__ int cur[256];
    int t = threadIdx.x, b = blockIdx.x;
    int gn = b * 256 + t;
    cur[t] = (gn < NN) ? offs[gn] : NE;
    __syncthreads();
    int bs = base2[b * SWG], be = base2[(b + 1) * SWG];
    for (int e = bs + t; e < be; e += 256) {
        unsigned int rec = ebuck[e];
        int slot = atomicAdd(&cur[(rec >> 16) & 255], 1);
        ssrc[slot] = (int)(rec & 0xffffu);
    }
}

// ---------------- p = x @ u  ->  p8 [N,8] fp32 (h<6 valid) ----------------
__global__ void __launch_bounds__(256) k_compute_p6(const unsigned short* __restrict__ x0b,
                                                    const void* __restrict__ u,
                                                    float* __restrict__ p8,
                                                    const int* __restrict__ flags) {
    int f32 = flags[0];
    int wave = (blockIdx.x * blockDim.x + threadIdx.x) >> 6;
    int lane = threadIdx.x & 63;
    if (wave >= NN) return;
    float acc[HH] = {0, 0, 0, 0, 0, 0};
    if (lane < 6) {
        float xv = u2f(x0b[(size_t)wave * 8 + lane]);
#pragma unroll
        for (int h = 0; h < HH; h++) acc[h] = xv * ldf(u, lane * HH + h, f32);
    }
#pragma unroll
    for (int off = 4; off > 0; off >>= 1) {
#pragma unroll
        for (int h = 0; h < HH; h++) acc[h] += __shfl_down(acc[h], off, 64);
    }
    if (lane == 0) {
#pragma unroll
        for (int h = 0; h < HH; h++) p8[(size_t)wave * 8 + h] = acc[h];
    }
}

__global__ void __launch_bounds__(256) k_compute_p128(const unsigned short* __restrict__ x,
                                                      const void* __restrict__ u,
                                                      float* __restrict__ p8,
                                                      const int* __restrict__ flags) {
    int f32 = flags[0];
    int wave = (blockIdx.x * blockDim.x + threadIdx.x) >> 6;
    int lane = threadIdx.x & 63;
    if (wave >= NN) return;
    unsigned int w = *(const unsigned int*)(x + (size_t)wave * 128 + 2 * lane);
    float x0 = lo2f(w);
    float x1 = hi2f(w);
    float acc[HH];
#pragma unroll
    for (int h = 0; h < HH; h++)
        acc[h] = x0 * ldf(u, (2 * lane) * HH + h, f32) + x1 * ldf(u, (2 * lane + 1) * HH + h, f32);
#pragma unroll
    for (int off = 32; off > 0; off >>= 1) {
#pragma unroll
        for (int h = 0; h < HH; h++) acc[h] += __shfl_down(acc[h], off, 64);
    }
    if (lane == 0) {
#pragma unroll
        for (int h = 0; h < HH; h++) p8[(size_t)wave * 8 + h] = acc[h];
    }
}

// ---------------- fused softmax + aggregation, CIN=128 (LDS-free) ----------
// 256 threads = 4 waves, wave per node. Chunk = 64 edges: phase A (all
// lanes) computes fp32 q + row offset into lane registers; phase B gets
// them via v_readlane and gathers x dwords directly (8 loads in flight),
// f32x2 pk_fma accumulate. Tail rounded to x8 with q=0 padding.
__global__ void __launch_bounds__(256) k_agg128(const unsigned short* __restrict__ xb,
                                                const float* __restrict__ p8,
                                                const void* __restrict__ cvec,
                                                const int* __restrict__ ssrc,
                                                const int* __restrict__ offs,
                                                unsigned short* __restrict__ agg,
                                                const int* __restrict__ flags) {
    int f32 = flags[0];
    int lane = threadIdx.x & 63;
    int node = (blockIdx.x * blockDim.x + threadIdx.x) >> 6;
    if (node >= NN) return;
    int s0 = offs[node], s1 = offs[node + 1];
    int deg = s1 - s0;
    float scale = 1.0f / (float)(deg > 0 ? deg : 1);
    const float* pn = p8 + (size_t)node * 8;
    float pd[HH];
#pragma unroll
    for (int h = 0; h < HH; h++) pd[h] = pn[h] - ldf(cvec, h, f32);

    f32x2 a[HH] = {};
    for (int base = s0; base < s1; base += 64) {
        int cnt = (s1 - base < 64) ? (s1 - base) : 64;
        // ---- phase A: lane = edge; q + row offset stay in registers ----
        float q0 = 0, q1 = 0, q2 = 0, q3 = 0, q4 = 0, q5 = 0;
        unsigned int rowElem = 0;
        {
            int e = base + lane;
            if (e < s1) {
                int j = ssrc[e];
                const float* pj = p8 + (size_t)j * 8;
                float4 pa = *(const float4*)pj;
                float2 pb = *(const float2*)(pj + 4);
                float t0 = pa.x - pd[0], t1 = pa.y - pd[1], t2 = pa.z - pd[2];
                float t3 = pa.w - pd[3], t4 = pb.x - pd[4], t5 = pb.y - pd[5];
                float mx = fmaxf(fmaxf(fmaxf(t0, t1), fmaxf(t2, t3)), fmaxf(t4, t5));
                q0 = __expf(t0 - mx); q1 = __expf(t1 - mx); q2 = __expf(t2 - mx);
                q3 = __expf(t3 - mx); q4 = __expf(t4 - mx); q5 = __expf(t5 - mx);
                float inv = 1.0f / (q0 + q1 + q2 + q3 + q4 + q5);
                q0 *= inv; q1 *= inv; q2 *= inv; q3 *= inv; q4 *= inv; q5 *= inv;
                rowElem = (unsigned int)j * 128u;
            }
        }
        // ---- phase B: readlane broadcast + direct gather, 8 in flight ----
        int cnt8 = (cnt + 7) & ~7;
        for (int s = 0; s < cnt8; s += 8) {
            unsigned int xw[8];
#pragma unroll
            for (int u = 0; u < 8; u++) {
                unsigned int ro =
                    (unsigned int)__builtin_amdgcn_readlane((int)rowElem, s + u);
                xw[u] = *(const unsigned int*)(xb + (size_t)ro + 2 * lane);
            }
#pragma unroll
            for (int u = 0; u < 8; u++) {
                f32x2 xx;
                xx.x = lo2f(xw[u]);
                xx.y = hi2f(xw[u]);
                f32x2 v0 = rlf(q0, s + u), v1 = rlf(q1, s + u), v2 = rlf(q2, s + u);
                f32x2 v3 = rlf(q3, s + u), v4 = rlf(q4, s + u), v5 = rlf(q5, s + u);
                a[0] = __builtin_elementwise_fma(v0, xx, a[0]);
                a[1] = __builtin_elementwise_fma(v1, xx, a[1]);
                a[2] = __builtin_elementwise_fma(v2, xx, a[2]);
                a[3] = __builtin_elementwise_fma(v3, xx, a[3]);
                a[4] = __builtin_elementwise_fma(v4, xx, a[4]);
                a[5] = __builtin_elementwise_fma(v5, xx, a[5]);
            }
        }
    }
    unsigned short* ar = agg + (size_t)node * 768;
#pragma unroll
    for (int h = 0; h < HH; h++) {
        *(unsigned int*)(ar + h * 128 + 2 * lane) = pk2(a[h].x * scale, a[h].y * scale);
    }
}

// ---------------- fused softmax + aggregation, CIN=6 (DMA staged) ---------
__global__ void __launch_bounds__(256) k_agg6(const unsigned short* __restrict__ xb,
                                              const float* __restrict__ p8,
                                              const void* __restrict__ cvec,
                                              const int* __restrict__ ssrc,
                                              const int* __restrict__ offs,
                                              float* __restrict__ agg,
                                              const int* __restrict__ flags) {
    __shared__ unsigned short stage6[4][64 * 8];     // 4 KB: 64 rows x 16 B
    __shared__ float qsf[4][64][8];                  // 8 KB: q[6] + rowbyte bits
    int f32 = flags[0];
    int wid = threadIdx.x >> 6, lane = threadIdx.x & 63;
    int node = (blockIdx.x * blockDim.x + threadIdx.x) >> 6;
    if (node >= NN) return;
    int s0 = offs[node], s1 = offs[node + 1];
    int deg = s1 - s0;
    float scale = 1.0f / (float)(deg > 0 ? deg : 1);
    const float* pn = p8 + (size_t)node * 8;
    float pd[HH];
#pragma unroll
    for (int h = 0; h < HH; h++) pd[h] = pn[h] - ldf(cvec, h, f32);

    float acc6 = 0.f;
    int hh6 = lane / 6, kk6 = lane - hh6 * 6;
    const char* xbase = (const char*)xb;
    for (int base = s0; base < s1; base += 64) {
        int cnt = (s1 - base < 64) ? (s1 - base) : 64;
        {
            int e = base + lane;
            float q0 = 0, q1 = 0, q2 = 0, q3 = 0, q4 = 0, q5 = 0;
            unsigned int rowByte = 0;
            if (e < s1) {
                int j = ssrc[e];
                const float* pj = p8 + (size_t)j * 8;
                float4 pa = *(const float4*)pj;
                float2 pb = *(const float2*)(pj + 4);
                float t0 = pa.x - pd[0], t1 = pa.y - pd[1], t2 = pa.z - pd[2];
                float t3 = pa.w - pd[3], t4 = pb.x - pd[4], t5 = pb.y - pd[5];
                float mx = fmaxf(fmaxf(fmaxf(t0, t1), fmaxf(t2, t3)), fmaxf(t4, t5));
                q0 = __expf(t0 - mx); q1 = __expf(t1 - mx); q2 = __expf(t2 - mx);
                q3 = __expf(t3 - mx); q4 = __expf(t4 - mx); q5 = __expf(t5 - mx);
                float inv = 1.0f / (q0 + q1 + q2 + q3 + q4 + q5);
                q0 *= inv; q1 *= inv; q2 *= inv; q3 *= inv; q4 *= inv; q5 *= inv;
                rowByte = (unsigned int)j * 16u;
            }
            float4 qa = {q0, q1, q2, q3};
            float4 qb = {q4, q5, __uint_as_float(rowByte), 0.f};
            *(float4*)&qsf[wid][lane][0] = qa;
            *(float4*)&qsf[wid][lane][4] = qb;
        }
        __builtin_amdgcn_sched_barrier(0);
#pragma unroll
        for (int t = 0; t < 4; t++) {
            int r = t * 16 + (lane >> 2);
            unsigned int rb = __float_as_uint(qsf[wid][r][6]);
            dma4(xbase + rb + (lane & 3) * 4, &stage6[wid][t * 128]);
        }
        __builtin_amdgcn_s_waitcnt(0x0f70);          // vmcnt(0) only
        __builtin_amdgcn_sched_barrier(0);
        if (lane < 36) {
            for (int s = 0; s < cnt; s++) {
                float qh = qsf[wid][s][hh6];
                float xv = u2f(stage6[wid][s * 8 + kk6]);
                acc6 = fmaf(qh, xv, acc6);
            }
        }
        __builtin_amdgcn_sched_barrier(0);
    }
    if (lane < 36) agg[(size_t)node * 36 + lane] = acc6 * scale;
}

// ---------------- fused weight repacks ----------------
__global__ void k_repack_all(const void* __restrict__ W1, const void* __restrict__ W2,
                             const void* __restrict__ W3, const void* __restrict__ W4,
                             float* __restrict__ wstk1, unsigned short* __restrict__ wt2,
                             unsigned short* __restrict__ wt3, float* __restrict__ wstk4,
                             const int* __restrict__ flags) {
    int f32 = flags[0];
    int idx = blockIdx.x * blockDim.x + threadIdx.x;
    if (idx < 4608) {
        int f = idx & 127, m = idx >> 7;
        int h = m / 6, k = m - h * 6;
        wstk1[idx] = ldf(W1, k * 768 + h * 128 + f, f32);
        return;
    }
    idx -= 4608;
    if (idx < 98304) {
        int f = idx / 768, m = idx % 768;
        int h = m >> 7, kk = m & 127;
        wt2[idx] = f2bu(ldf(W2, kk * 768 + h * 128 + f, f32));
        return;
    }
    idx -= 98304;
    if (idx < 98304) {
        int f = idx / 768, m = idx % 768;
        int h = m >> 7, kk = m & 127;
        wt3[idx] = f2bu(ldf(W3, kk * 768 + h * 128 + f, f32));
        return;
    }
    idx -= 98304;
    if (idx < 2304) {
        int f = idx % 3, m = idx / 3;
        int h = m >> 7, k = m & 127;
        wstk4[idx] = ldf(W4, k * 18 + h * 3 + f, f32);
    }
}

// ---------------- layer-1 GEMM (fp32, K=36), writes bf16 x ----------------
__global__ void __launch_bounds__(256) k_gemm_f32(const float* __restrict__ A,
                                                  const float* __restrict__ B,
                                                  const void* __restrict__ bias,
                                                  unsigned short* __restrict__ C,
                                                  int M, int K, int relu,
                                                  const int* __restrict__ flags) {
    int f32 = flags[0];
    __shared__ float As[16][68];
    __shared__ float Bs[16][128];
    int tid = threadIdx.x;
    int tx = tid & 15;
    int ty = tid >> 4;
    int bm = blockIdx.x * 64;
    int arow = tid >> 2, ak = (tid & 3) * 4;
    int brow = tid >> 4, bcol = (tid & 15) * 8;
    float acc[4][8] = {};
    for (int k0 = 0; k0 < K; k0 += 16) {
        float4 av = {0, 0, 0, 0};
        int gr = bm + arow;
        if (gr < M && (k0 + ak) < K) av = *(const float4*)(A + (size_t)gr * K + k0 + ak);
        As[ak + 0][arow] = av.x;
        As[ak + 1][arow] = av.y;
        As[ak + 2][arow] = av.z;
        As[ak + 3][arow] = av.w;
        float4 bv0 = {0, 0, 0, 0}, bv1 = {0, 0, 0, 0};
        if ((k0 + brow) < K) {
            const float* bp = B + (size_t)(k0 + brow) * 128 + bcol;
            bv0 = *(const float4*)bp;
            bv1 = *(const float4*)(bp + 4);
        }
        *(float4*)&Bs[brow][bcol]     = bv0;
        *(float4*)&Bs[brow][bcol + 4] = bv1;
        __syncthreads();
#pragma unroll
        for (int kk = 0; kk < 16; kk++) {
            float a_[4], b_[8];
#pragma unroll
            for (int j = 0; j < 4; j++) a_[j] = As[kk][ty * 4 + j];
#pragma unroll
            for (int j = 0; j < 8; j++) b_[j] = Bs[kk][tx * 8 + j];
#pragma unroll
            for (int i = 0; i < 4; i++)
#pragma unroll
                for (int j = 0; j < 8; j++) acc[i][j] = fmaf(a_[i], b_[j], acc[i][j]);
        }
        __syncthreads();
    }
#pragma unroll
    for (int i = 0; i < 4; i++) {
        int row = bm + ty * 4 + i;
        if (row >= M) continue;
#pragma unroll
        for (int j = 0; j < 8; j++) {
            int col = tx * 8 + j;
            float v = acc[i][j] + ldf(bias, col, f32);
            if (relu) v = fmaxf(v, 0.f);
            C[(size_t)row * 128 + col] = f2bu(v);
        }
    }
}

// ---------------- MFMA GEMM: C[M,128] = A[M,768]bf16 @ Wt^T + bias, ReLU ----
__global__ void __launch_bounds__(256) k_gemm_mfma(const unsigned short* __restrict__ A,
                                                   const unsigned short* __restrict__ Bt,
                                                   const void* __restrict__ bias,
                                                   unsigned short* __restrict__ C,
                                                   int M, int relu,
                                                   const int* __restrict__ flags) {
    constexpr int K = 768, BK = 64;
    __shared__ unsigned short As[64][72];
    __shared__ unsigned short Bs[128][72];
    int f32 = flags[0];
    int tid = threadIdx.x;
    int lane = tid & 63, wid = tid >> 6;
    int wm = wid & 1, wn = wid >> 1;
    int bm = blockIdx.x * 64;
    int l15 = lane & 15, lq = lane >> 4;
    f32x4 acc[2][4] = {};

    for (int k0 = 0; k0 < K; k0 += BK) {
#pragma unroll
        for (int cc = 0; cc < 2; cc++) {
            int c = tid + cc * 256;
            int r = c >> 3, kc = (c & 7) * 8;
            bf16x8 av = {};
            int gr = bm + r;
            if (gr < M) av = *(const bf16x8*)(A + (size_t)gr * K + k0 + kc);
            *(bf16x8*)&As[r][kc] = av;
        }
#pragma unroll
        for (int cc = 0; cc < 4; cc++) {
            int c = tid + cc * 256;
            int n = c >> 3, kc = (c & 7) * 8;
            *(bf16x8*)&Bs[n][kc] = *(const bf16x8*)(Bt + (size_t)n * K + k0 + kc);
        }
        __syncthreads();
#pragma unroll
        for (int ks = 0; ks < BK; ks += 32) {
            int koff = ks + lq * 8;
            bf16x8 af[2], bfr[4];
#pragma unroll
            for (int tm = 0; tm < 2; tm++)
                af[tm] = *(const bf16x8*)&As[wm * 32 + tm * 16 + l15][koff];
#pragma unroll
            for (int tn = 0; tn < 4; tn++)
                bfr[tn] = *(const bf16x8*)&Bs[wn * 64 + tn * 16 + l15][koff];
#pragma unroll
            for (int tm = 0; tm < 2; tm++)
#pragma unroll
                for (int tn = 0; tn < 4; tn++)
                    acc[tm][tn] = __builtin_amdgcn_mfma_f32_16x16x32_bf16(
                        af[tm], bfr[tn], acc[tm][tn], 0, 0, 0);
        }
        __syncthreads();
    }
#pragma unroll
    for (int tm = 0; tm < 2; tm++) {
#pragma unroll
        for (int tn = 0; tn < 4; tn++) {
            int col = wn * 64 + tn * 16 + l15;
            float bv = ldf(bias, col, f32);
#pragma unroll
            for (int r = 0; r < 4; r++) {
                int row = bm + wm * 32 + tm * 16 + lq * 4 + r;
                if (row < M) {
                    float v = acc[tm][tn][r] + bv;
                    if (relu) v = fmaxf(v, 0.f);
                    C[(size_t)row * 128 + col] = f2bu(v);
                }
            }
        }
    }
}

// ---------------- final layer ----------------
__global__ void __launch_bounds__(256) k_final(const unsigned short* __restrict__ agg,
                                               const float* __restrict__ wstk,
                                               const void* __restrict__ bias,
                                               void* __restrict__ out,
                                               const int* __restrict__ flags) {
    int f32 = flags[0];
    int node = (blockIdx.x * blockDim.x + threadIdx.x) >> 6;
    int lane = threadIdx.x & 63;
    if (node >= NN) return;
    float f0 = 0, f1 = 0, f2 = 0;
    const unsigned short* ar = agg + (size_t)node * 768;
#pragma unroll
    for (int it = 0; it < 6; it++) {
        int m = it * 128 + 2 * lane;
        unsigned int w = *(const unsigned int*)(ar + m);
        float a0 = lo2f(w);
        float a1 = hi2f(w);
        f0 += a0 * wstk[m * 3 + 0] + a1 * wstk[m * 3 + 3];
        f1 += a0 * wstk[m * 3 + 1] + a1 * wstk[m * 3 + 4];
        f2 += a0 * wstk[m * 3 + 2] + a1 * wstk[m * 3 + 5];
    }
#pragma unroll
    for (int off = 32; off > 0; off >>= 1) {
        f0 += __shfl_down(f0, off, 64);
        f1 += __shfl_down(f1, off, 64);
        f2 += __shfl_down(f2, off, 64);
    }
    if (lane == 0) {
        float r0 = f0 + ldf(bias, 0, f32);
        float r1 = f1 + ldf(bias, 1, f32);
        float r2 = f2 + ldf(bias, 2, f32);
        if (f32) {
            float* o = (float*)out;
            o[(size_t)node * 3 + 0] = r0;
            o[(size_t)node * 3 + 1] = r1;
            o[(size_t)node * 3 + 2] = r2;
        } else {
            __hip_bfloat16* o = (__hip_bfloat16*)out;
            o[(size_t)node * 3 + 0] = __float2bfloat16(r0);
            o[(size_t)node * 3 + 1] = __float2bfloat16(r1);
            o[(size_t)node * 3 + 2] = __float2bfloat16(r2);
        }
    }
}

extern "C" void kernel_launch(void* const* d_in, const int* in_sizes, int n_in,
                              void* d_out, int out_size, void* d_ws, size_t ws_size,
                              hipStream_t stream) {
    (void)in_sizes; (void)n_in; (void)out_size; (void)ws_size;
    const void* pos = d_in[0];
    const void* nrm = d_in[1];
    const int* ei = (const int*)d_in[2];
    const void* W[4] = {d_in[3], d_in[7], d_in[11], d_in[15]};
    const void* U[4] = {d_in[4], d_in[8], d_in[12], d_in[16]};
    const void* Cc[4] = {d_in[5], d_in[9], d_in[13], d_in[17]};
    const void* Bb[4] = {d_in[6], d_in[10], d_in[14], d_in[18]};

    char* wp = (char*)d_ws;
    auto alloc = [&](size_t b) { void* r = (void*)wp; wp += (b + 255) & ~(size_t)255; return r; };
    unsigned short* xA  = (unsigned short*)alloc((size_t)NN * 128 * 2);
    unsigned short* xB  = (unsigned short*)alloc((size_t)NN * 128 * 2);
    unsigned short* x0b = (unsigned short*)alloc((size_t)NN * 8 * 2);
    float* p8     = (float*)alloc((size_t)NN * 8 * 4);
    int*   counts = (int*)alloc((size_t)NN * 4);
    int*   offs   = (int*)alloc((size_t)(NN + 1) * 4);
    int*   cntT   = (int*)alloc((size_t)NBK * SWG * 4);
    int*   base2  = (int*)alloc((size_t)(NBK * SWG + 1) * 4);
    int*   flags  = (int*)alloc(256);
    int*   ssrc   = (int*)alloc((size_t)NE * 4);
    unsigned int* ebuck = (unsigned int*)alloc((size_t)NE * 4);
    void*  aggv   = alloc((size_t)NN * 768 * 2);
    float* wstk1  = (float*)alloc((size_t)36 * 128 * 4);
    unsigned short* wt2 = (unsigned short*)alloc((size_t)128 * 768 * 2);
    unsigned short* wt3 = (unsigned short*)alloc((size_t)128 * 768 * 2);
    float* wstk4  = (float*)alloc((size_t)768 * 3 * 4);
    unsigned short* agg_h = (unsigned short*)aggv;
    float* agg_f = (float*)aggv;

    const int NB = (NN + 255) / 256;
    const int NWB = (NN * 64 + 255) / 256;      // 256-thread wave-per-node grids
    const int GB = (NN + 63) / 64;

    k_detect<<<1, 256, 0, stream>>>(pos, ei, flags);
    hipMemsetAsync(counts, 0, (size_t)NN * 4, stream);
    k_sortA<<<SWG, 256, 0, stream>>>(ei, counts, cntT, flags);
    k_scan2<<<2, 1024, 0, stream>>>(counts, offs, NN, cntT, base2, NBK * SWG);
    k_sortB<<<SWG, 256, 0, stream>>>(ei, base2, ebuck, flags);
    k_sortC<<<NBK, 256, 0, stream>>>(ebuck, base2, offs, ssrc);
    k_build_x0<<<NB, 256, 0, stream>>>(pos, nrm, x0b, flags);
    k_repack_all<<<(203520 + 255) / 256, 256, 0, stream>>>(W[0], W[1], W[2], W[3],
                                                           wstk1, wt2, wt3, wstk4, flags);

    // ---- layer 1: 6 -> 128, relu ----
    k_compute_p6<<<NWB, 256, 0, stream>>>(x0b, U[0], p8, flags);
    k_agg6<<<NWB, 256, 0, stream>>>(x0b, p8, Cc[0], ssrc, offs, agg_f, flags);
    k_gemm_f32<<<GB, 256, 0, stream>>>(agg_f, wstk1, Bb[0], xA, NN, 36, 1, flags);

    // ---- layer 2: 128 -> 128, relu ----
    k_compute_p128<<<NWB, 256, 0, stream>>>(xA, U[1], p8, flags);
    k_agg128<<<NWB, 256, 0, stream>>>(xA, p8, Cc[1], ssrc, offs, agg_h, flags);
    k_gemm_mfma<<<GB, 256, 0, stream>>>(agg_h, wt2, Bb[1], xB, NN, 1, flags);

    // ---- layer 3: 128 -> 128, relu ----
    k_compute_p128<<<NWB, 256, 0, stream>>>(xB, U[2], p8, flags);
    k_agg128<<<NWB, 256, 0, stream>>>(xB, p8, Cc[2], ssrc, offs, agg_h, flags);
    k_gemm_mfma<<<GB, 256, 0, stream>>>(agg_h, wt3, Bb[2], xA, NN, 1, flags);

    // ---- layer 4: 128 -> 3 ----
    k_compute_p128<<<NWB, 256, 0, stream>>>(xA, U[3], p8, flags);
    k_agg128<<<NWB, 256, 0, stream>>>(xA, p8, Cc[3], ssrc, offs, agg_h, flags);
    k_final<<<NWB, 256, 0, stream>>>(agg_h, wstk4, Bb[3], d_out, flags);
}